// Round 1
// baseline (504.304 us; speedup 1.0000x reference)
//
#include <hip/hip_runtime.h>
#include <math.h>

#define B_ 16
#define S_ 1024
#define D_ 128
#define N_ 128
#define BS_ (B_*S_)   // 16384 query rows
#define BN_ (B_*N_)   // 2048 prototype rows

__device__ __forceinline__ float gelu_exact(float x) {
    return 0.5f * x * (1.0f + erff(x * 0.70710678118654752440f));
}

// ---------------------------------------------------------------------------
// K1: Ht[b][m][d] = gelu( sum_s x[b][s][d] * w_n1[s][m] + b_n1[m] )
// grid (16, 16): b, m-strip of 8.  256 threads, thread tile 2d x 2m.
// ---------------------------------------------------------------------------
__global__ __launch_bounds__(256) void k1_hidden(const float* __restrict__ x,
                                                 const float* __restrict__ w1,
                                                 const float* __restrict__ b1,
                                                 float* __restrict__ Ht) {
    __shared__ float xs[32][132];
    __shared__ float w1s[32][8];
    const int b  = blockIdx.x;
    const int m0 = blockIdx.y * 8;
    const int tid = threadIdx.x;
    const int tx = tid & 63;   // d-pair index: d = 2*tx
    const int ty = tid >> 6;   // 0..3, m-pair: m = m0 + 2*ty + mi
    float acc[2][2];
    acc[0][0] = acc[0][1] = b1[m0 + 2*ty];
    acc[1][0] = acc[1][1] = b1[m0 + 2*ty + 1];
    for (int s0 = 0; s0 < S_; s0 += 32) {
        {
            const int ss = tid >> 3, p = tid & 7;
            const float* gx = x + ((size_t)b * S_ + s0 + ss) * D_ + p * 16;
            float4 v0 = ((const float4*)gx)[0];
            float4 v1 = ((const float4*)gx)[1];
            float4 v2 = ((const float4*)gx)[2];
            float4 v3 = ((const float4*)gx)[3];
            float* dst = &xs[ss][p * 16];
            ((float4*)dst)[0] = v0; ((float4*)dst)[1] = v1;
            ((float4*)dst)[2] = v2; ((float4*)dst)[3] = v3;
            w1s[ss][p] = w1[(size_t)(s0 + ss) * N_ + m0 + p];
        }
        __syncthreads();
        #pragma unroll
        for (int ss = 0; ss < 32; ++ss) {
            float2 a = *(const float2*)&xs[ss][2 * tx];
            float2 w = *(const float2*)&w1s[ss][2 * ty];
            acc[0][0] += w.x * a.x; acc[0][1] += w.x * a.y;
            acc[1][0] += w.y * a.x; acc[1][1] += w.y * a.y;
        }
        __syncthreads();
    }
    #pragma unroll
    for (int mi = 0; mi < 2; ++mi) {
        float2 o;
        o.x = gelu_exact(acc[mi][0]);
        o.y = gelu_exact(acc[mi][1]);
        *(float2*)&Ht[((size_t)b * N_ + m0 + 2*ty + mi) * D_ + 2 * tx] = o;
    }
}

// ---------------------------------------------------------------------------
// K2: proto[b*128+n][d] = sum_m Ht[b][m][d] * w_n2[m][n] + b_n2[n]
// grid (16, 16): b, n-strip of 8.  Writes directly to output slot 1.
// ---------------------------------------------------------------------------
__global__ __launch_bounds__(256) void k2_proto(const float* __restrict__ Ht,
                                                const float* __restrict__ w2,
                                                const float* __restrict__ b2,
                                                float* __restrict__ proto_out) {
    __shared__ float hs[32][132];
    __shared__ float w2s[32][8];
    const int b  = blockIdx.x;
    const int n0 = blockIdx.y * 8;
    const int tid = threadIdx.x;
    const int tx = tid & 63;
    const int ty = tid >> 6;
    float acc[2][2];
    acc[0][0] = acc[0][1] = b2[n0 + 2*ty];
    acc[1][0] = acc[1][1] = b2[n0 + 2*ty + 1];
    for (int m0 = 0; m0 < N_; m0 += 32) {
        {
            const int ss = tid >> 3, p = tid & 7;
            const float* gh = Ht + ((size_t)b * N_ + m0 + ss) * D_ + p * 16;
            float4 v0 = ((const float4*)gh)[0];
            float4 v1 = ((const float4*)gh)[1];
            float4 v2 = ((const float4*)gh)[2];
            float4 v3 = ((const float4*)gh)[3];
            float* dst = &hs[ss][p * 16];
            ((float4*)dst)[0] = v0; ((float4*)dst)[1] = v1;
            ((float4*)dst)[2] = v2; ((float4*)dst)[3] = v3;
            w2s[ss][p] = w2[(size_t)(m0 + ss) * N_ + n0 + p];
        }
        __syncthreads();
        #pragma unroll
        for (int ss = 0; ss < 32; ++ss) {
            float2 a = *(const float2*)&hs[ss][2 * tx];
            float2 w = *(const float2*)&w2s[ss][2 * ty];
            acc[0][0] += w.x * a.x; acc[0][1] += w.x * a.y;
            acc[1][0] += w.y * a.x; acc[1][1] += w.y * a.y;
        }
        __syncthreads();
    }
    #pragma unroll
    for (int ni = 0; ni < 2; ++ni) {
        float2 o = make_float2(acc[ni][0], acc[ni][1]);
        *(float2*)&proto_out[((size_t)b * N_ + n0 + 2*ty + ni) * D_ + 2 * tx] = o;
    }
}

// ---------------------------------------------------------------------------
// K3: reciprocal L2 norms. wave-per-row. rows [0,16384) -> x, [16384,18432) -> proto
// ---------------------------------------------------------------------------
__global__ __launch_bounds__(256) void k3_norms(const float* __restrict__ x,
                                                const float* __restrict__ proto,
                                                float* __restrict__ xinv,
                                                float* __restrict__ pinv) {
    const int w = blockIdx.x * 4 + (threadIdx.x >> 6);
    const int lane = threadIdx.x & 63;
    const float* src;
    float* dst;
    if (w < BS_) { src = x + (size_t)w * D_;            dst = xinv + w; }
    else         { int r = w - BS_;
                   src = proto + (size_t)r * D_;        dst = pinv + r; }
    float2 v = *(const float2*)(src + 2 * lane);
    float s = v.x * v.x + v.y * v.y;
    #pragma unroll
    for (int m = 1; m < 64; m <<= 1) s += __shfl_xor(s, m, 64);
    if (lane == 0) *dst = 1.0f / sqrtf(s);
}

// ---------------------------------------------------------------------------
// K4: fused cosine-sim attention (flash-style), QT=32 queries/block, KT=64 keys/tile
// 256 threads: tx = tid&31, ty = tid>>5 (q-quad).  LDS = 61.7 KB -> 2 blocks/CU.
// proto tile stored with per-row chunk rotation slot=(chunk+(k>>1))&31 so both
// feature-major (score) and row-major (PV) reads avoid degenerate bank patterns.
// ---------------------------------------------------------------------------
__global__ __launch_bounds__(256) void k4_attn(const float* __restrict__ x,
                                               const int*   __restrict__ umask,
                                               const float* __restrict__ proto,
                                               const float* __restrict__ xinv,
                                               const float* __restrict__ pinv,
                                               float* __restrict__ prompt) {
    __shared__ float xqT[128][36];     // [feature][query], query pre-scaled by 1/||x||
    __shared__ float kts[64 * 132];    // rotated proto tile
    __shared__ float pT[64][36];       // exp'd scores, [key][query]
    __shared__ float pvs[64];          // 1/||proto|| for tile
    const int tid = threadIdx.x;
    const int q0 = blockIdx.x * 32;
    const int tx = tid & 31;
    const int ty = tid >> 5;           // 0..7 -> queries 4*ty..4*ty+3

    // stage queries transposed, pre-scaled by 1/norm
    {
        const int q = tid >> 3, p = tid & 7;
        const float xi = xinv[q0 + q];
        const float* gx = x + (size_t)(q0 + q) * D_ + p * 16;
        #pragma unroll
        for (int i = 0; i < 4; ++i) {
            float4 v = ((const float4*)gx)[i];
            const int c = p * 16 + 4 * i;
            xqT[c + 0][q] = v.x * xi;
            xqT[c + 1][q] = v.y * xi;
            xqT[c + 2][q] = v.z * xi;
            xqT[c + 3][q] = v.w * xi;
        }
    }
    float mr[4];
    #pragma unroll
    for (int i = 0; i < 4; ++i)
        mr[i] = -10000.0f * (1.0f - (float)umask[q0 + 4 * ty + i]);

    float m_run[4] = {-1e30f, -1e30f, -1e30f, -1e30f};
    float l_run[4] = {0.f, 0.f, 0.f, 0.f};
    float acc[4][4] = {};

    for (int t = 0; t < BN_; t += 64) {
        // ---- stage proto tile (rotated) + pinv tile ----
        #pragma unroll
        for (int i = 0; i < 8; ++i) {
            const int g = tid + 256 * i;           // float4 index within tile
            const int k = g >> 5, cc = g & 31;     // row, chunk
            float4 v = *(const float4*)&proto[(size_t)(t + k) * D_ + cc * 4];
            const int slot = (cc + (k >> 1)) & 31;
            *(float4*)(kts + k * 132 + slot * 4) = v;
        }
        if (tid < 64) pvs[tid] = pinv[t + tid];
        __syncthreads();

        // ---- phase 1: scores s[q 4][k 2] for k = 2*tx, 2*tx+1 ----
        float s[4][2] = {};
        {
            const float* rowA = kts + (2 * tx) * 132;
            const float* rowB = kts + (2 * tx + 1) * 132;
            #pragma unroll 4
            for (int kq = 0; kq < 32; ++kq) {
                const int slot = ((kq + tx) & 31) * 4;
                float4 va = *(const float4*)(rowA + slot);
                float4 vb = *(const float4*)(rowB + slot);
                const float* xcol = &xqT[kq * 4][4 * ty];
                float4 x0 = *(const float4*)(xcol);
                float4 x1 = *(const float4*)(xcol + 36);
                float4 x2 = *(const float4*)(xcol + 72);
                float4 x3 = *(const float4*)(xcol + 108);
                s[0][0] += x0.x*va.x; s[1][0] += x0.y*va.x; s[2][0] += x0.z*va.x; s[3][0] += x0.w*va.x;
                s[0][1] += x0.x*vb.x; s[1][1] += x0.y*vb.x; s[2][1] += x0.z*vb.x; s[3][1] += x0.w*vb.x;
                s[0][0] += x1.x*va.y; s[1][0] += x1.y*va.y; s[2][0] += x1.z*va.y; s[3][0] += x1.w*va.y;
                s[0][1] += x1.x*vb.y; s[1][1] += x1.y*vb.y; s[2][1] += x1.z*vb.y; s[3][1] += x1.w*vb.y;
                s[0][0] += x2.x*va.z; s[1][0] += x2.y*va.z; s[2][0] += x2.z*va.z; s[3][0] += x2.w*va.z;
                s[0][1] += x2.x*vb.z; s[1][1] += x2.y*vb.z; s[2][1] += x2.z*vb.z; s[3][1] += x2.w*vb.z;
                s[0][0] += x3.x*va.w; s[1][0] += x3.y*va.w; s[2][0] += x3.z*va.w; s[3][0] += x3.w*va.w;
                s[0][1] += x3.x*vb.w; s[1][1] += x3.y*vb.w; s[2][1] += x3.z*vb.w; s[3][1] += x3.w*vb.w;
            }
        }
        // epilogue: cosine scale + mask (row-constant, kept for rounding parity)
        {
            const float pvA = pvs[2 * tx], pvB = pvs[2 * tx + 1];
            #pragma unroll
            for (int i = 0; i < 4; ++i) {
                s[i][0] = s[i][0] * pvA + mr[i];
                s[i][1] = s[i][1] * pvB + mr[i];
            }
        }
        // ---- online softmax (32-lane groups share a q-quad) ----
        float f[4];
        #pragma unroll
        for (int i = 0; i < 4; ++i) {
            float tm = fmaxf(s[i][0], s[i][1]);
            #pragma unroll
            for (int m = 1; m < 32; m <<= 1) tm = fmaxf(tm, __shfl_xor(tm, m, 32));
            const float nm = fmaxf(m_run[i], tm);
            f[i] = expf(m_run[i] - nm);
            float e0 = expf(s[i][0] - nm);
            float e1 = expf(s[i][1] - nm);
            float es = e0 + e1;
            #pragma unroll
            for (int m = 1; m < 32; m <<= 1) es += __shfl_xor(es, m, 32);
            l_run[i] = l_run[i] * f[i] + es;
            m_run[i] = nm;
            s[i][0] = e0; s[i][1] = e1;
        }
        // write exp'd scores transposed
        #pragma unroll
        for (int jj = 0; jj < 2; ++jj) {
            float4 e4 = make_float4(s[0][jj], s[1][jj], s[2][jj], s[3][jj]);
            *(float4*)&pT[2 * tx + jj][4 * ty] = e4;
        }
        __syncthreads();

        // ---- PV: acc[q 4][d 4], d = 4*tx..4*tx+3 ----
        #pragma unroll
        for (int i = 0; i < 4; ++i) {
            acc[i][0] *= f[i]; acc[i][1] *= f[i];
            acc[i][2] *= f[i]; acc[i][3] *= f[i];
        }
        #pragma unroll 4
        for (int k = 0; k < 64; ++k) {
            float4 p4 = *(const float4*)&pT[k][4 * ty];
            float4 v  = *(const float4*)(kts + k * 132 + (((tx + (k >> 1)) & 31) << 2));
            acc[0][0] += p4.x*v.x; acc[0][1] += p4.x*v.y; acc[0][2] += p4.x*v.z; acc[0][3] += p4.x*v.w;
            acc[1][0] += p4.y*v.x; acc[1][1] += p4.y*v.y; acc[1][2] += p4.y*v.z; acc[1][3] += p4.y*v.w;
            acc[2][0] += p4.z*v.x; acc[2][1] += p4.z*v.y; acc[2][2] += p4.z*v.z; acc[2][3] += p4.z*v.w;
            acc[3][0] += p4.w*v.x; acc[3][1] += p4.w*v.y; acc[3][2] += p4.w*v.z; acc[3][3] += p4.w*v.w;
        }
        __syncthreads();
    }
    // normalize + store
    #pragma unroll
    for (int i = 0; i < 4; ++i) {
        const float inv = 1.0f / l_run[i];
        float4 o = make_float4(acc[i][0]*inv, acc[i][1]*inv, acc[i][2]*inv, acc[i][3]*inv);
        *(float4*)&prompt[(size_t)(q0 + 4 * ty + i) * D_ + 4 * tx] = o;
    }
}

// ---------------------------------------------------------------------------
// K_res: out2 = x @ w_p + b_p   (block = 8 rows, 256 threads)
// ---------------------------------------------------------------------------
__global__ __launch_bounds__(256) void k_res(const float* __restrict__ x,
                                             const float* __restrict__ wp,
                                             const float* __restrict__ bp,
                                             float* __restrict__ out2) {
    __shared__ float xsr[8][132];
    const int r0 = blockIdx.x * 8;
    const int tid = threadIdx.x;
    const int c = tid & 127, rh = tid >> 7;
    {
        const int r = tid >> 5, c4 = (tid & 31) * 4;
        *(float4*)&xsr[r][c4] = *(const float4*)&x[(size_t)(r0 + r) * D_ + c4];
    }
    __syncthreads();
    float a[4];
    #pragma unroll
    for (int i = 0; i < 4; ++i) a[i] = bp[c];
    for (int k = 0; k < D_; ++k) {
        const float w = wp[(size_t)k * D_ + c];
        #pragma unroll
        for (int i = 0; i < 4; ++i) a[i] += xsr[rh * 4 + i][k] * w;
    }
    #pragma unroll
    for (int i = 0; i < 4; ++i)
        out2[(size_t)(r0 + rh * 4 + i) * D_ + c] = a[i];
}

// ---------------------------------------------------------------------------
// K5: out0 = gelu(prompt @ w_d1 + b_d1) @ w_d2 + b_d2 + res
// ---------------------------------------------------------------------------
__global__ __launch_bounds__(256) void k5_mlp(const float* __restrict__ prompt,
                                              const float* __restrict__ w1,
                                              const float* __restrict__ b1,
                                              const float* __restrict__ w2,
                                              const float* __restrict__ b2,
                                              const float* __restrict__ res,
                                              float* __restrict__ out0) {
    __shared__ float ps[8][132];
    __shared__ float t1s[8][132];
    const int r0 = blockIdx.x * 8;
    const int tid = threadIdx.x;
    const int c = tid & 127, rh = tid >> 7;
    {
        const int r = tid >> 5, c4 = (tid & 31) * 4;
        *(float4*)&ps[r][c4] = *(const float4*)&prompt[(size_t)(r0 + r) * D_ + c4];
    }
    __syncthreads();
    float a[4];
    #pragma unroll
    for (int i = 0; i < 4; ++i) a[i] = b1[c];
    for (int k = 0; k < D_; ++k) {
        const float w = w1[(size_t)k * D_ + c];
        #pragma unroll
        for (int i = 0; i < 4; ++i) a[i] += ps[rh * 4 + i][k] * w;
    }
    #pragma unroll
    for (int i = 0; i < 4; ++i) t1s[rh * 4 + i][c] = gelu_exact(a[i]);
    __syncthreads();
    #pragma unroll
    for (int i = 0; i < 4; ++i) a[i] = b2[c];
    for (int k = 0; k < D_; ++k) {
        const float w = w2[(size_t)k * D_ + c];
        #pragma unroll
        for (int i = 0; i < 4; ++i) a[i] += t1s[rh * 4 + i][k] * w;
    }
    #pragma unroll
    for (int i = 0; i < 4; ++i) {
        const size_t idx = (size_t)(r0 + rh * 4 + i) * D_ + c;
        out0[idx] = a[i] + res[idx];
    }
}

// ---------------------------------------------------------------------------
extern "C" void kernel_launch(void* const* d_in, const int* in_sizes, int n_in,
                              void* d_out, int out_size, void* d_ws, size_t ws_size,
                              hipStream_t stream) {
    const float* x    = (const float*)d_in[0];
    const int*   um   = (const int*)  d_in[1];
    const float* w_n1 = (const float*)d_in[2];
    const float* b_n1 = (const float*)d_in[3];
    const float* w_n2 = (const float*)d_in[4];
    const float* b_n2 = (const float*)d_in[5];
    const float* w_d1 = (const float*)d_in[6];
    const float* b_d1 = (const float*)d_in[7];
    const float* w_d2 = (const float*)d_in[8];
    const float* b_d2 = (const float*)d_in[9];
    const float* w_p  = (const float*)d_in[10];
    const float* b_p  = (const float*)d_in[11];

    float* out0 = (float*)d_out;                    // prompt_mlp + res [16384,128]
    float* out1 = out0 + (size_t)BS_ * D_;          // proto            [2048,128]
    float* out2 = out1 + (size_t)BN_ * D_;          // res              [16384,128]

    float* Ht     = (float*)d_ws;                   // [16,128,128]  1 MB
    float* prompt = Ht + (size_t)B_ * N_ * D_;      // [16384,128]   8 MB
    float* xinv   = prompt + (size_t)BS_ * D_;      // [16384]
    float* pinv   = xinv + BS_;                     // [2048]

    hipLaunchKernelGGL(k1_hidden, dim3(16, 16), dim3(256), 0, stream, x, w_n1, b_n1, Ht);
    hipLaunchKernelGGL(k2_proto,  dim3(16, 16), dim3(256), 0, stream, Ht, w_n2, b_n2, out1);
    hipLaunchKernelGGL(k3_norms,  dim3(4608),   dim3(256), 0, stream, x, out1, xinv, pinv);
    hipLaunchKernelGGL(k_res,     dim3(2048),   dim3(256), 0, stream, x, w_p, b_p, out2);
    hipLaunchKernelGGL(k4_attn,   dim3(512),    dim3(256), 0, stream, x, um, out1, xinv, pinv, prompt);
    hipLaunchKernelGGL(k5_mlp,    dim3(2048),   dim3(256), 0, stream, prompt, w_d1, b_d1, w_d2, b_d2, out2, out0);
}

// Round 2
// 207.435 us; speedup vs baseline: 2.4311x; 2.4311x over previous
//
#include <hip/hip_runtime.h>
#include <math.h>

#define B_ 16
#define S_ 1024
#define D_ 128
#define N_ 128
#define BS_ (B_*S_)   // 16384 query rows
#define BN_ (B_*N_)   // 2048 prototype rows

typedef __attribute__((ext_vector_type(8))) short short8b;
typedef __attribute__((ext_vector_type(4))) float f32x4;
typedef __attribute__((ext_vector_type(4))) unsigned short us4;

__device__ __forceinline__ float gelu_exact(float x) {
    return 0.5f * x * (1.0f + erff(x * 0.70710678118654752440f));
}

// exact RNE float->bf16 (matches numpy/jax rounding)
__device__ __forceinline__ unsigned short f2bf(float f) {
    unsigned u = __builtin_bit_cast(unsigned, f);
    unsigned r = (u + 0x7FFFu + ((u >> 16) & 1u)) >> 16;
    return (unsigned short)r;
}

__device__ __forceinline__ void gl16(const void* g, void* l) {
    __builtin_amdgcn_global_load_lds((const __attribute__((address_space(1))) unsigned int*)g,
                                     (__attribute__((address_space(3))) unsigned int*)l,
                                     16, 0, 0);
}

// ---------------------------------------------------------------------------
// K1: Ht[b][m][d] = gelu( sum_s x[b][s][d] * w_n1[s][m] + b_n1[m] )
// ---------------------------------------------------------------------------
__global__ __launch_bounds__(256) void k1_hidden(const float* __restrict__ x,
                                                 const float* __restrict__ w1,
                                                 const float* __restrict__ b1,
                                                 float* __restrict__ Ht) {
    __shared__ float xs[32][132];
    __shared__ float w1s[32][8];
    const int b  = blockIdx.x;
    const int m0 = blockIdx.y * 8;
    const int tid = threadIdx.x;
    const int tx = tid & 63;
    const int ty = tid >> 6;
    float acc[2][2];
    acc[0][0] = acc[0][1] = b1[m0 + 2*ty];
    acc[1][0] = acc[1][1] = b1[m0 + 2*ty + 1];
    for (int s0 = 0; s0 < S_; s0 += 32) {
        {
            const int ss = tid >> 3, p = tid & 7;
            const float* gx = x + ((size_t)b * S_ + s0 + ss) * D_ + p * 16;
            float4 v0 = ((const float4*)gx)[0];
            float4 v1 = ((const float4*)gx)[1];
            float4 v2 = ((const float4*)gx)[2];
            float4 v3 = ((const float4*)gx)[3];
            float* dst = &xs[ss][p * 16];
            ((float4*)dst)[0] = v0; ((float4*)dst)[1] = v1;
            ((float4*)dst)[2] = v2; ((float4*)dst)[3] = v3;
            w1s[ss][p] = w1[(size_t)(s0 + ss) * N_ + m0 + p];
        }
        __syncthreads();
        #pragma unroll
        for (int ss = 0; ss < 32; ++ss) {
            float2 a = *(const float2*)&xs[ss][2 * tx];
            float2 w = *(const float2*)&w1s[ss][2 * ty];
            acc[0][0] += w.x * a.x; acc[0][1] += w.x * a.y;
            acc[1][0] += w.y * a.x; acc[1][1] += w.y * a.y;
        }
        __syncthreads();
    }
    #pragma unroll
    for (int mi = 0; mi < 2; ++mi) {
        float2 o;
        o.x = gelu_exact(acc[mi][0]);
        o.y = gelu_exact(acc[mi][1]);
        *(float2*)&Ht[((size_t)b * N_ + m0 + 2*ty + mi) * D_ + 2 * tx] = o;
    }
}

// ---------------------------------------------------------------------------
// K2: proto = Ht @ w_n2 + b_n2 ; also emits bf16 copy + bf16 transposed copy
// ---------------------------------------------------------------------------
__global__ __launch_bounds__(256) void k2_proto(const float* __restrict__ Ht,
                                                const float* __restrict__ w2,
                                                const float* __restrict__ b2,
                                                float* __restrict__ proto_out,
                                                unsigned short* __restrict__ pbf,
                                                unsigned short* __restrict__ pbfT) {
    __shared__ float hs[32][132];
    __shared__ float w2s[32][8];
    const int b  = blockIdx.x;
    const int n0 = blockIdx.y * 8;
    const int tid = threadIdx.x;
    const int tx = tid & 63;
    const int ty = tid >> 6;
    float acc[2][2];
    acc[0][0] = acc[0][1] = b2[n0 + 2*ty];
    acc[1][0] = acc[1][1] = b2[n0 + 2*ty + 1];
    for (int m0 = 0; m0 < N_; m0 += 32) {
        {
            const int ss = tid >> 3, p = tid & 7;
            const float* gh = Ht + ((size_t)b * N_ + m0 + ss) * D_ + p * 16;
            float4 v0 = ((const float4*)gh)[0];
            float4 v1 = ((const float4*)gh)[1];
            float4 v2 = ((const float4*)gh)[2];
            float4 v3 = ((const float4*)gh)[3];
            float* dst = &hs[ss][p * 16];
            ((float4*)dst)[0] = v0; ((float4*)dst)[1] = v1;
            ((float4*)dst)[2] = v2; ((float4*)dst)[3] = v3;
            w2s[ss][p] = w2[(size_t)(m0 + ss) * N_ + n0 + p];
        }
        __syncthreads();
        #pragma unroll
        for (int ss = 0; ss < 32; ++ss) {
            float2 a = *(const float2*)&hs[ss][2 * tx];
            float2 w = *(const float2*)&w2s[ss][2 * ty];
            acc[0][0] += w.x * a.x; acc[0][1] += w.x * a.y;
            acc[1][0] += w.y * a.x; acc[1][1] += w.y * a.y;
        }
        __syncthreads();
    }
    #pragma unroll
    for (int ni = 0; ni < 2; ++ni) {
        const int n  = n0 + 2*ty + ni;
        const int bn = b * N_ + n;
        const int d  = 2 * tx;
        float2 o = make_float2(acc[ni][0], acc[ni][1]);
        *(float2*)&proto_out[(size_t)bn * D_ + d] = o;
        unsigned short h0 = f2bf(o.x), h1 = f2bf(o.y);
        *(unsigned int*)&pbf[(size_t)bn * D_ + d] = (unsigned)h0 | ((unsigned)h1 << 16);
        pbfT[(size_t)d       * BN_ + bn] = h0;
        pbfT[(size_t)(d + 1) * BN_ + bn] = h1;
    }
}

// ---------------------------------------------------------------------------
// K3: reciprocal L2 norms
// ---------------------------------------------------------------------------
__global__ __launch_bounds__(256) void k3_norms(const float* __restrict__ x,
                                                const float* __restrict__ proto,
                                                float* __restrict__ xinv,
                                                float* __restrict__ pinv) {
    const int w = blockIdx.x * 4 + (threadIdx.x >> 6);
    const int lane = threadIdx.x & 63;
    const float* src;
    float* dst;
    if (w < BS_) { src = x + (size_t)w * D_;      dst = xinv + w; }
    else         { int r = w - BS_;
                   src = proto + (size_t)r * D_;  dst = pinv + r; }
    float2 v = *(const float2*)(src + 2 * lane);
    float s = v.x * v.x + v.y * v.y;
    #pragma unroll
    for (int m = 1; m < 64; m <<= 1) s += __shfl_xor(s, m, 64);
    if (lane == 0) *dst = 1.0f / sqrtf(s);
}

// ---------------------------------------------------------------------------
// K4 (MFMA): fused cosine-sim attention, fixed softmax max = 1 (cos <= 1),
// mask dropped (row-constant => softmax-invariant).
// 512 blocks x 256 thr. Wave w: qg=w&1 (16 queries), kh=w>>1 (1024-key half).
// Swapped QK^T: S^T = mfma(K_frag, X_frag) so P is wave-local.
// K tile [64k][128c] + Vt tile [128d][64k] staged via global_load_lds with
// XOR-chunk pre-swizzled global sources (bank-optimal b128 reads).
// ---------------------------------------------------------------------------
__global__ __launch_bounds__(256) void k4_attn_mfma(const float* __restrict__ x,
                                                    const unsigned short* __restrict__ pbf,
                                                    const unsigned short* __restrict__ pbfT,
                                                    const float* __restrict__ xinv,
                                                    const float* __restrict__ pinv,
                                                    float* __restrict__ prompt) {
    __shared__ __align__(16) unsigned short K_lds[2][64 * 128];   // 16 KB per half
    __shared__ __align__(16) unsigned short Vt_lds[2][128 * 64];  // 16 KB per half
    __shared__ __align__(16) unsigned short P_lds[4][16 * 64];    // 2 KB per wave
    __shared__ __align__(16) float pinv_lds[BN_];                 // 8 KB

    const int tid  = threadIdx.x;
    const int lane = tid & 63;
    const int w    = tid >> 6;
    const int qg   = w & 1;
    const int kh   = w >> 1;
    const int l15  = lane & 15;
    const int lh   = lane >> 4;
    const int ht   = tid & 127;          // thread index within key-half
    const int q0   = blockIdx.x * 32;

    // stage pinv (whole array) into LDS
    for (int i = tid; i < BN_ / 4; i += 256)
        ((f32x4*)pinv_lds)[i] = ((const f32x4*)pinv)[i];

    // X B-fragments in registers for the whole kernel (pre-scaled by 1/||x||)
    const int qrow = q0 + qg * 16 + l15;
    const float xi = xinv[qrow];
    short8b Xf[4];
    #pragma unroll
    for (int kk = 0; kk < 4; ++kk) {
        const float* px = x + (size_t)qrow * D_ + kk * 32 + lh * 8;
        f32x4 a = *(const f32x4*)px;
        f32x4 b = *(const f32x4*)(px + 4);
        short8b r;
        r[0] = (short)f2bf(a[0]*xi); r[1] = (short)f2bf(a[1]*xi);
        r[2] = (short)f2bf(a[2]*xi); r[3] = (short)f2bf(a[3]*xi);
        r[4] = (short)f2bf(b[0]*xi); r[5] = (short)f2bf(b[1]*xi);
        r[6] = (short)f2bf(b[2]*xi); r[7] = (short)f2bf(b[3]*xi);
        Xf[kk] = r;
    }

    float lsum = 0.0f;
    f32x4 acc[8];
    #pragma unroll
    for (int nb = 0; nb < 8; ++nb) acc[nb] = (f32x4){0.f, 0.f, 0.f, 0.f};

    unsigned short* KB = K_lds[kh];
    unsigned short* VB = Vt_lds[kh];

    for (int it = 0; it < 16; ++it) {
        const int t0 = kh * 1024 + it * 64;
        __syncthreads();   // previous tile fully consumed
        // ---- stage K tile + Vt tile (128 threads per half, 8+8 chunks each) ----
        #pragma unroll
        for (int i = 0; i < 8; ++i) {
            const int s = ht + 128 * i;
            {   // K tile: row-major [key][c], chunk = 16B of 8 bf16
                const int key = s >> 4, chs = s & 15;
                const int ch  = chs ^ (key & 7);
                gl16(pbf + (size_t)(t0 + key) * D_ + ch * 8, KB + (size_t)s * 8);
            }
            {   // Vt tile: row-major [d][key]
                const int d = s >> 3, c2s = s & 7;
                const int c2 = c2s ^ (d & 7);
                gl16(pbfT + (size_t)d * BN_ + t0 + c2 * 8, VB + (size_t)s * 8);
            }
        }
        __syncthreads();   // drains vmcnt: tile visible

        // ---- swapped QK^T: S^T[key][q] ----
        f32x4 S0 = (f32x4){0,0,0,0}, S1 = S0, S2 = S0, S3 = S0;
        #pragma unroll
        for (int kk = 0; kk < 4; ++kk) {
            const int cchunk = kk * 4 + lh;
            #pragma unroll
            for (int kt = 0; kt < 4; ++kt) {
                const int key = kt * 16 + l15;
                const int chunk = cchunk ^ (key & 7);
                short8b Kf = *(const short8b*)(KB + key * 128 + chunk * 8);
                f32x4& S = (kt == 0) ? S0 : (kt == 1) ? S1 : (kt == 2) ? S2 : S3;
                S = __builtin_amdgcn_mfma_f32_16x16x32_bf16(Kf, Xf[kk], S, 0, 0, 0);
            }
        }

        // ---- scale by pinv, exp(s-1), pack bf16, write wave-local P ----
        unsigned short* PW = P_lds[w];
        #pragma unroll
        for (int kt = 0; kt < 4; ++kt) {
            const f32x4 S = (kt == 0) ? S0 : (kt == 1) ? S1 : (kt == 2) ? S2 : S3;
            const f32x4 pv4 = *(const f32x4*)&pinv_lds[t0 + kt * 16 + lh * 4];
            us4 pk;
            #pragma unroll
            for (int jr = 0; jr < 4; ++jr) {
                float sv = S[jr] * pv4[jr];
                float p  = exp2f((sv - 1.0f) * 1.442695040888963f);
                lsum += p;
                pk[jr] = f2bf(p);
            }
            const int chunk = (kt * 2 + (lh >> 1)) ^ (l15 & 7);
            *(us4*)&PW[l15 * 64 + chunk * 8 + (lh & 1) * 4] = pk;
        }

        // ---- PV: acc[q][d] += P @ V ----
        short8b Pf0, Pf1;
        {
            const int c0 = (0 * 4 + lh) ^ (l15 & 7);
            const int c1 = (1 * 4 + lh) ^ (l15 & 7);
            Pf0 = *(const short8b*)&PW[l15 * 64 + c0 * 8];
            Pf1 = *(const short8b*)&PW[l15 * 64 + c1 * 8];
        }
        const int vc0 = (0 * 4 + lh) ^ (l15 & 7);
        const int vc1 = (1 * 4 + lh) ^ (l15 & 7);
        #pragma unroll
        for (int nb = 0; nb < 8; ++nb) {
            const int d = nb * 16 + l15;
            short8b Vf0 = *(const short8b*)(VB + d * 64 + vc0 * 8);
            short8b Vf1 = *(const short8b*)(VB + d * 64 + vc1 * 8);
            acc[nb] = __builtin_amdgcn_mfma_f32_16x16x32_bf16(Pf0, Vf0, acc[nb], 0, 0, 0);
            acc[nb] = __builtin_amdgcn_mfma_f32_16x16x32_bf16(Pf1, Vf1, acc[nb], 0, 0, 0);
        }
    }

    // ---- reduce lsum across lh groups (same q = l15) ----
    lsum += __shfl_xor(lsum, 16, 64);
    lsum += __shfl_xor(lsum, 32, 64);

    // ---- combine key-halves through LDS, normalize, store ----
    __syncthreads();
    float* Obuf = (float*)&K_lds[0][0];   // 16 KB: [32 q][128 d], col-XOR swizzled
    float* lbuf = pinv_lds;               // 32 floats
    if (kh == 1) {
        #pragma unroll
        for (int nb = 0; nb < 8; ++nb) {
            #pragma unroll
            for (int jr = 0; jr < 4; ++jr) {
                const int row = qg * 16 + lh * 4 + jr;
                const int col = nb * 16 + l15;
                Obuf[row * 128 + (col ^ ((row & 7) << 2))] = acc[nb][jr];
            }
        }
        if (lane < 16) lbuf[qg * 16 + l15] = lsum;
    }
    __syncthreads();
    if (kh == 0) {
        const float inv = 1.0f / (lsum + lbuf[qg * 16 + l15]);
        #pragma unroll
        for (int nb = 0; nb < 8; ++nb) {
            #pragma unroll
            for (int jr = 0; jr < 4; ++jr) {
                const int row = qg * 16 + lh * 4 + jr;
                const int col = nb * 16 + l15;
                float o = acc[nb][jr] + Obuf[row * 128 + (col ^ ((row & 7) << 2))];
                float rl = __shfl(inv, lh * 4 + jr, 64);
                prompt[(size_t)(q0 + row) * D_ + col] = o * rl;
            }
        }
    }
}

// ---------------------------------------------------------------------------
// K_res: out2 = x @ w_p + b_p
// ---------------------------------------------------------------------------
__global__ __launch_bounds__(256) void k_res(const float* __restrict__ x,
                                             const float* __restrict__ wp,
                                             const float* __restrict__ bp,
                                             float* __restrict__ out2) {
    __shared__ float xsr[8][132];
    const int r0 = blockIdx.x * 8;
    const int tid = threadIdx.x;
    const int c = tid & 127, rh = tid >> 7;
    {
        const int r = tid >> 5, c4 = (tid & 31) * 4;
        *(float4*)&xsr[r][c4] = *(const float4*)&x[(size_t)(r0 + r) * D_ + c4];
    }
    __syncthreads();
    float a[4];
    #pragma unroll
    for (int i = 0; i < 4; ++i) a[i] = bp[c];
    for (int k = 0; k < D_; ++k) {
        const float w = wp[(size_t)k * D_ + c];
        #pragma unroll
        for (int i = 0; i < 4; ++i) a[i] += xsr[rh * 4 + i][k] * w;
    }
    #pragma unroll
    for (int i = 0; i < 4; ++i)
        out2[(size_t)(r0 + rh * 4 + i) * D_ + c] = a[i];
}

// ---------------------------------------------------------------------------
// K5: out0 = gelu(prompt @ w_d1 + b_d1) @ w_d2 + b_d2 + res
// ---------------------------------------------------------------------------
__global__ __launch_bounds__(256) void k5_mlp(const float* __restrict__ prompt,
                                              const float* __restrict__ w1,
                                              const float* __restrict__ b1,
                                              const float* __restrict__ w2,
                                              const float* __restrict__ b2,
                                              const float* __restrict__ res,
                                              float* __restrict__ out0) {
    __shared__ float ps[8][132];
    __shared__ float t1s[8][132];
    const int r0 = blockIdx.x * 8;
    const int tid = threadIdx.x;
    const int c = tid & 127, rh = tid >> 7;
    {
        const int r = tid >> 5, c4 = (tid & 31) * 4;
        *(float4*)&ps[r][c4] = *(const float4*)&prompt[(size_t)(r0 + r) * D_ + c4];
    }
    __syncthreads();
    float a[4];
    #pragma unroll
    for (int i = 0; i < 4; ++i) a[i] = b1[c];
    for (int k = 0; k < D_; ++k) {
        const float w = w1[(size_t)k * D_ + c];
        #pragma unroll
        for (int i = 0; i < 4; ++i) a[i] += ps[rh * 4 + i][k] * w;
    }
    #pragma unroll
    for (int i = 0; i < 4; ++i) t1s[rh * 4 + i][c] = gelu_exact(a[i]);
    __syncthreads();
    #pragma unroll
    for (int i = 0; i < 4; ++i) a[i] = b2[c];
    for (int k = 0; k < D_; ++k) {
        const float w = w2[(size_t)k * D_ + c];
        #pragma unroll
        for (int i = 0; i < 4; ++i) a[i] += t1s[rh * 4 + i][k] * w;
    }
    #pragma unroll
    for (int i = 0; i < 4; ++i) {
        const size_t idx = (size_t)(r0 + rh * 4 + i) * D_ + c;
        out0[idx] = a[i] + res[idx];
    }
}

// ---------------------------------------------------------------------------
extern "C" void kernel_launch(void* const* d_in, const int* in_sizes, int n_in,
                              void* d_out, int out_size, void* d_ws, size_t ws_size,
                              hipStream_t stream) {
    const float* x    = (const float*)d_in[0];
    const float* w_n1 = (const float*)d_in[2];
    const float* b_n1 = (const float*)d_in[3];
    const float* w_n2 = (const float*)d_in[4];
    const float* b_n2 = (const float*)d_in[5];
    const float* w_d1 = (const float*)d_in[6];
    const float* b_d1 = (const float*)d_in[7];
    const float* w_d2 = (const float*)d_in[8];
    const float* b_d2 = (const float*)d_in[9];
    const float* w_p  = (const float*)d_in[10];
    const float* b_p  = (const float*)d_in[11];

    float* out0 = (float*)d_out;                    // prompt_mlp + res [16384,128]
    float* out1 = out0 + (size_t)BS_ * D_;          // proto            [2048,128]
    float* out2 = out1 + (size_t)BN_ * D_;          // res              [16384,128]

    float* Ht     = (float*)d_ws;                   // [16,128,128]
    float* prompt = Ht + (size_t)B_ * N_ * D_;      // [16384,128]
    float* xinv   = prompt + (size_t)BS_ * D_;      // [16384]
    float* pinv   = xinv + BS_;                     // [2048]
    unsigned short* pbf  = (unsigned short*)(pinv + BN_);   // [2048,128] bf16
    unsigned short* pbfT = pbf + (size_t)BN_ * D_;          // [128,2048] bf16

    hipLaunchKernelGGL(k1_hidden,    dim3(16, 16), dim3(256), 0, stream, x, w_n1, b_n1, Ht);
    hipLaunchKernelGGL(k2_proto,     dim3(16, 16), dim3(256), 0, stream, Ht, w_n2, b_n2, out1, pbf, pbfT);
    hipLaunchKernelGGL(k3_norms,     dim3(4608),   dim3(256), 0, stream, x, out1, xinv, pinv);
    hipLaunchKernelGGL(k_res,        dim3(2048),   dim3(256), 0, stream, x, w_p, b_p, out2);
    hipLaunchKernelGGL(k4_attn_mfma, dim3(512),    dim3(256), 0, stream, x, pbf, pbfT, xinv, pinv, prompt);
    hipLaunchKernelGGL(k5_mlp,       dim3(2048),   dim3(256), 0, stream, prompt, w_d1, b_d1, w_d2, b_d2, out2, out0);
}

// Round 4
// 177.098 us; speedup vs baseline: 2.8476x; 1.1713x over previous
//
#include <hip/hip_runtime.h>
#include <math.h>

#define B_ 16
#define S_ 1024
#define D_ 128
#define N_ 128
#define BS_ (B_*S_)   // 16384 query rows
#define BN_ (B_*N_)   // 2048 prototype rows
#define LOG2E 1.442695040888963f

typedef __attribute__((ext_vector_type(8))) short short8b;
typedef __attribute__((ext_vector_type(4))) float f32x4;
typedef __attribute__((ext_vector_type(4))) unsigned short us4;
typedef __attribute__((ext_vector_type(4))) unsigned int u32x4;

__device__ __forceinline__ float gelu_exact(float x) {
    return 0.5f * x * (1.0f + erff(x * 0.70710678118654752440f));
}

// RNE float->bf16
__device__ __forceinline__ unsigned short f2bf(float f) {
    unsigned u = __builtin_bit_cast(unsigned, f);
    unsigned r = (u + 0x7FFFu + ((u >> 16) & 1u)) >> 16;
    return (unsigned short)r;
}
__device__ __forceinline__ unsigned int pk2(float lo, float hi) {
    return (unsigned)f2bf(lo) | ((unsigned)f2bf(hi) << 16);
}

__device__ __forceinline__ void gl16(const void* g, void* l) {
    __builtin_amdgcn_global_load_lds((const __attribute__((address_space(1))) unsigned int*)g,
                                     (__attribute__((address_space(3))) unsigned int*)l,
                                     16, 0, 0);
}

// MFMA convention (HW-verified in R1 k4):
//   mfma(Af, Bf, C): C[i][j] = sum_c A[i][c]*B[j][c]
//   A/B frag: lane(l15,lh) holds row l15, elems c = kc*32 + lh*8 + (0..7)
//   C/D:      lane(l15,lh) reg jr holds C[i = 4*lh + jr][j = l15]  (+16*tile)
// Staged tiles use slot = chunk ^ (row&7) pre-swizzle on the GLOBAL source,
// linear LDS dest (global_load_lds rule), same XOR on reads.

// ---------------------------------------------------------------------------
// K0a: x prep: xnbf = bf16(x/||x||) row-major; xT[b][d][s] = bf16(x) transposed;
// xnorm = ||x_row||.  grid (16 b x 16 s-tiles of 64) = 256 blocks, 256 thr.
// ---------------------------------------------------------------------------
__global__ __launch_bounds__(256) void k0a_xprep(const float* __restrict__ x,
                                                 unsigned short* __restrict__ xnbf,
                                                 unsigned short* __restrict__ xT,
                                                 float* __restrict__ xnorm) {
    __shared__ __align__(16) unsigned int T2[128 * 32]; // [d][sp] u32, byte = d*128 + (sp*4 ^ ((d>>3)&7)<<4)
    const int b  = blockIdx.x >> 4;
    const int s0 = (blockIdx.x & 15) * 64;
    const int t  = threadIdx.x;
    const int rp = t >> 3;        // 0..31 row-pair
    const int q  = t & 7;         // 16-col chunk
    const int row0 = s0 + 2 * rp;
    const float* p0 = x + ((size_t)b * S_ + row0) * D_ + q * 16;
    const float* p1 = p0 + D_;
    f32x4 a[4], c[4];
    #pragma unroll
    for (int i = 0; i < 4; ++i) { a[i] = ((const f32x4*)p0)[i]; c[i] = ((const f32x4*)p1)[i]; }
    float sa = 0.f, sc = 0.f;
    #pragma unroll
    for (int i = 0; i < 4; ++i)
        #pragma unroll
        for (int j = 0; j < 4; ++j) { sa += a[i][j]*a[i][j]; sc += c[i][j]*c[i][j]; }
    sa += __shfl_xor(sa, 1); sa += __shfl_xor(sa, 2); sa += __shfl_xor(sa, 4);
    sc += __shfl_xor(sc, 1); sc += __shfl_xor(sc, 2); sc += __shfl_xor(sc, 4);
    const float na = sqrtf(sa), nc = sqrtf(sc);
    if (q == 0) {
        xnorm[(size_t)b*S_ + row0]     = na;
        xnorm[(size_t)b*S_ + row0 + 1] = nc;
    }
    const float ia = 1.0f / na, ic = 1.0f / nc;
    unsigned int pk[8];
    #pragma unroll
    for (int i = 0; i < 4; ++i) {
        pk[2*i]   = pk2(a[i][0]*ia, a[i][1]*ia);
        pk[2*i+1] = pk2(a[i][2]*ia, a[i][3]*ia);
    }
    *(u32x4*)(xnbf + ((size_t)b*S_ + row0)*D_ + q*16)     = *(u32x4*)&pk[0];
    *(u32x4*)(xnbf + ((size_t)b*S_ + row0)*D_ + q*16 + 8) = *(u32x4*)&pk[4];
    #pragma unroll
    for (int i = 0; i < 4; ++i) {
        pk[2*i]   = pk2(c[i][0]*ic, c[i][1]*ic);
        pk[2*i+1] = pk2(c[i][2]*ic, c[i][3]*ic);
    }
    *(u32x4*)(xnbf + ((size_t)b*S_ + row0 + 1)*D_ + q*16)     = *(u32x4*)&pk[0];
    *(u32x4*)(xnbf + ((size_t)b*S_ + row0 + 1)*D_ + q*16 + 8) = *(u32x4*)&pk[4];
    // transpose tile (unnormalized), s-pairs packed in u32
    #pragma unroll
    for (int i = 0; i < 4; ++i)
        #pragma unroll
        for (int j = 0; j < 4; ++j) {
            const int d = q*16 + i*4 + j;
            *(unsigned int*)((char*)T2 + d*128 + ((rp*4) ^ (((d>>3)&7)<<4))) =
                pk2(a[i][j], c[i][j]);
        }
    __syncthreads();
    const int d  = t >> 1;
    const int hf = t & 1;
    unsigned short* dst = xT + ((size_t)(b*128 + d))*1024 + s0 + hf*32;
    #pragma unroll
    for (int cI = 0; cI < 4; ++cI) {
        const int sp0 = hf*16 + cI*4;
        u32x4 v = *(u32x4*)((char*)T2 + d*128 + ((sp0*4) ^ (((d>>3)&7)<<4)));
        *(u32x4*)(dst + cI*8) = v;
    }
}

// ---------------------------------------------------------------------------
// K0b: weight transposes to bf16: dst[c][r] = bf16(src[r][c]).  64x64 tiles.
// blocks 0..31: w1 (1024x128); 32..47: w2/wp/wd1/wd2 (128x128), 4 tiles each.
// ---------------------------------------------------------------------------
__global__ __launch_bounds__(256) void k0b_wprep(const float* __restrict__ w1,
                                                 const float* __restrict__ w2,
                                                 const float* __restrict__ wp,
                                                 const float* __restrict__ wd1,
                                                 const float* __restrict__ wd2,
                                                 unsigned short* __restrict__ w1T,
                                                 unsigned short* __restrict__ w2T,
                                                 unsigned short* __restrict__ wpT,
                                                 unsigned short* __restrict__ wd1T,
                                                 unsigned short* __restrict__ wd2T) {
    __shared__ __align__(16) unsigned int T2[64 * 32];
    const int bi = blockIdx.x;
    const float* src; unsigned short* dst; int R, r0, c0;
    if (bi < 32) {
        src = w1; dst = w1T; R = 1024;
        r0 = (bi >> 1) * 64; c0 = (bi & 1) * 64;
    } else {
        const int k = (bi - 32) >> 2, qd = (bi - 32) & 3;
        const float* ss[4] = {w2, wp, wd1, wd2};
        unsigned short* dd[4] = {w2T, wpT, wd1T, wd2T};
        src = ss[k]; dst = dd[k]; R = 128;
        r0 = (qd >> 1) * 64; c0 = (qd & 1) * 64;
    }
    const int t = threadIdx.x;
    const int rp = t >> 3, q = t & 7;   // row-pair, col-chunk of 8
    const float* p0 = src + (size_t)(r0 + 2*rp) * 128 + c0 + q*8;
    const float* p1 = p0 + 128;
    f32x4 a0 = ((const f32x4*)p0)[0], a1 = ((const f32x4*)p0)[1];
    f32x4 b0 = ((const f32x4*)p1)[0], b1 = ((const f32x4*)p1)[1];
    #pragma unroll
    for (int j = 0; j < 4; ++j) {
        int cc = q*8 + j;
        *(unsigned int*)((char*)T2 + cc*128 + ((rp*4) ^ (((cc>>3)&7)<<4))) = pk2(a0[j], b0[j]);
        cc = q*8 + 4 + j;
        *(unsigned int*)((char*)T2 + cc*128 + ((rp*4) ^ (((cc>>3)&7)<<4))) = pk2(a1[j], b1[j]);
    }
    __syncthreads();
    const int cI = t >> 2, qt = t & 3;
    unsigned short* od = dst + (size_t)(c0 + cI) * R + r0 + qt*16;
    #pragma unroll
    for (int u = 0; u < 2; ++u) {
        const int sp0 = qt*8 + u*4;
        u32x4 v = *(u32x4*)((char*)T2 + cI*128 + ((sp0*4) ^ (((cI>>3)&7)<<4)));
        *(u32x4*)(od + u*8) = v;
    }
}

// ---------------------------------------------------------------------------
// K12: fused proto pipeline, one block per batch b (16 blocks x 512 thr, 8 waves).
// Phase A: H[m][d] = sum_s w1T[m][s]*xT[d][s]  (K=1024, dbuf prefetch)
// gelu+b1 -> GT[d][m] bf16 in LDS.
// Phase B: proto[n][d] = sum_m w2T[n][m]*GT[d][m] + b2[n]
// Epilogue: out1 fp32, pbf = bf16(proto/||proto_row||), pbfT = bf16(proto)^T.
// ---------------------------------------------------------------------------
__global__ __launch_bounds__(512) void k12_proto(const unsigned short* __restrict__ xT,
                                                 const unsigned short* __restrict__ w1T,
                                                 const float* __restrict__ b_n1,
                                                 const unsigned short* __restrict__ w2T,
                                                 const float* __restrict__ b_n2,
                                                 float* __restrict__ out1,
                                                 unsigned short* __restrict__ pbf,
                                                 unsigned short* __restrict__ pbfT) {
    __shared__ __align__(16) unsigned short pool[2][2][128 * 64]; // [buf][0=w1T,1=xT] 64KB
    __shared__ __align__(16) unsigned short GT[128][136];         // 34.8KB [d][m] pad-136
    __shared__ float nrm[128][2];
    const int b = blockIdx.x;
    const int tid = threadIdx.x;
    const int w = tid >> 6, l = tid & 63, l15 = l & 15, lh = l >> 4;
    const int mb = (w & 3) * 32;      // phase A m-tiles
    const int db = (w >> 2) * 64;     // phase A d-tiles

    f32x4 acc[2][4] = {};

    #define STAGE_A(buf, itt)                                                        \
        { _Pragma("unroll")                                                          \
          for (int i = 0; i < 2; ++i) {                                              \
            const int s = tid + 512*i;                                               \
            const int r = s >> 3, chs = s & 7;                                       \
            gl16(w1T + (size_t)r*1024 + (itt)*64 + (chs ^ (r & 7))*8,                \
                 &pool[buf][0][s*8]);                                                \
            gl16(xT + ((size_t)(b*128 + r))*1024 + (itt)*64 + (chs ^ (r & 7))*8,     \
                 &pool[buf][1][s*8]);                                                \
          } }

    STAGE_A(0, 0)
    asm volatile("s_waitcnt vmcnt(0)");
    __syncthreads();
    int cur = 0;
    for (int it = 0; it < 16; ++it) {
        if (it < 15) {
            STAGE_A(cur ^ 1, it + 1)
        } else {
            // stage w2T into pool[0] (free: cur==1 at it==15)
            #pragma unroll
            for (int i = 0; i < 4; ++i) {
                const int s = tid + 512*i;
                const int r = s >> 4, chs = s & 15;
                gl16(w2T + (size_t)r*128 + (chs ^ (r & 7))*8,
                     ((unsigned short*)pool[0]) + s*8);
            }
        }
        const unsigned short* WA = pool[cur][0];
        const unsigned short* XA = pool[cur][1];
        #pragma unroll
        for (int kc = 0; kc < 2; ++kc) {
            short8b Af[2], Bf[4];
            #pragma unroll
            for (int mt = 0; mt < 2; ++mt) {
                const int m = mb + mt*16 + l15;
                Af[mt] = *(const short8b*)(WA + m*64 + ((kc*4 + lh) ^ (m & 7))*8);
            }
            #pragma unroll
            for (int dt = 0; dt < 4; ++dt) {
                const int d = db + dt*16 + l15;
                Bf[dt] = *(const short8b*)(XA + d*64 + ((kc*4 + lh) ^ (d & 7))*8);
            }
            #pragma unroll
            for (int mt = 0; mt < 2; ++mt)
                #pragma unroll
                for (int dt = 0; dt < 4; ++dt)
                    acc[mt][dt] = __builtin_amdgcn_mfma_f32_16x16x32_bf16(Af[mt], Bf[dt], acc[mt][dt], 0, 0, 0);
        }
        asm volatile("s_waitcnt vmcnt(0)");
        __syncthreads();
        cur ^= 1;
    }
    // gelu + bias -> GT[d][m]
    #pragma unroll
    for (int mt = 0; mt < 2; ++mt)
        #pragma unroll
        for (int dt = 0; dt < 4; ++dt)
            #pragma unroll
            for (int u = 0; u < 2; ++u) {
                const int m = mb + mt*16 + lh*4 + 2*u;
                const int d = db + dt*16 + l15;
                const float v0 = gelu_exact(acc[mt][dt][2*u]   + b_n1[m]);
                const float v1 = gelu_exact(acc[mt][dt][2*u+1] + b_n1[m+1]);
                *(unsigned int*)((char*)&GT[0][0] + d*272 + m*2) = pk2(v0, v1);
            }
    __syncthreads();
    // Phase B
    const unsigned short* W2 = (const unsigned short*)pool[0];
    f32x4 acc2[2][4] = {};
    #pragma unroll
    for (int kc = 0; kc < 4; ++kc) {
        short8b Af[2], Bf[4];
        #pragma unroll
        for (int nt = 0; nt < 2; ++nt) {
            const int n = mb + nt*16 + l15;
            Af[nt] = *(const short8b*)(W2 + n*128 + ((kc*4 + lh) ^ (n & 7))*8);
        }
        #pragma unroll
        for (int dt = 0; dt < 4; ++dt) {
            const int d = db + dt*16 + l15;
            Bf[dt] = *(const short8b*)((char*)&GT[0][0] + d*272 + kc*64 + lh*16);
        }
        #pragma unroll
        for (int nt = 0; nt < 2; ++nt)
            #pragma unroll
            for (int dt = 0; dt < 4; ++dt)
                acc2[nt][dt] = __builtin_amdgcn_mfma_f32_16x16x32_bf16(Af[nt], Bf[dt], acc2[nt][dt], 0, 0, 0);
    }
    // bias + out1 + norm partials
    #pragma unroll
    for (int nt = 0; nt < 2; ++nt) {
        #pragma unroll
        for (int jr = 0; jr < 4; ++jr) {
            const int n = mb + nt*16 + lh*4 + jr;
            const float bb = b_n2[n];
            float ps = 0.f;
            #pragma unroll
            for (int dt = 0; dt < 4; ++dt) {
                const int d = db + dt*16 + l15;
                const float v = acc2[nt][dt][jr] + bb;
                acc2[nt][dt][jr] = v;
                out1[((size_t)(b*128 + n))*128 + d] = v;
                ps += v * v;
            }
            ps += __shfl_xor(ps, 1); ps += __shfl_xor(ps, 2);
            ps += __shfl_xor(ps, 4); ps += __shfl_xor(ps, 8);
            if (l15 == 0) nrm[n][w >> 2] = ps;
        }
    }
    __syncthreads();
    // pbf (normalized) + TP (unnormalized transpose, swizzled)
    unsigned short* TP = (unsigned short*)pool[1];  // [128 d][128 n], byte ^ ((d&7)<<4)
    #pragma unroll
    for (int nt = 0; nt < 2; ++nt)
        #pragma unroll
        for (int jr = 0; jr < 4; ++jr) {
            const int n = mb + nt*16 + lh*4 + jr;
            const float pin = 1.0f / sqrtf(nrm[n][0] + nrm[n][1]);
            #pragma unroll
            for (int dt = 0; dt < 4; ++dt) {
                const int d = db + dt*16 + l15;
                pbf[((size_t)(b*128 + n))*128 + d] = f2bf(acc2[nt][dt][jr] * pin);
            }
        }
    #pragma unroll
    for (int nt = 0; nt < 2; ++nt)
        #pragma unroll
        for (int dt = 0; dt < 4; ++dt)
            #pragma unroll
            for (int u = 0; u < 2; ++u) {
                const int n0 = mb + nt*16 + lh*4 + 2*u;
                const int d = db + dt*16 + l15;
                *(unsigned int*)((char*)TP + d*256 + ((n0*2) ^ ((d & 7) << 4))) =
                    pk2(acc2[nt][dt][2*u], acc2[nt][dt][2*u+1]);
            }
    __syncthreads();
    if (tid < 256) {
        const int d = tid >> 1, hf = tid & 1;
        #pragma unroll
        for (int cI = 0; cI < 8; ++cI) {
            short8b v = *(const short8b*)((char*)TP + d*256 + ((hf*128 + cI*16) ^ ((d & 7) << 4)));
            *(short8b*)(pbfT + (size_t)d*BN_ + b*128 + hf*64 + cI*8) = v;
        }
    }
}

// ---------------------------------------------------------------------------
// K4: fused cosine attention. 256 blocks x 256 thr (4 waves).
// wave w: qg = w&1 (32 queries), kh = w>>1 (1024-key half). 16 tiles of 64 keys.
// Dual 16-q fragment sets share every K/V LDS read. Fixed softmax max = 1.
// pbf is pre-normalized (cosine direct). Output: pbm bf16 [16384][128].
// ---------------------------------------------------------------------------
__global__ __launch_bounds__(256) void k4_attn_mfma(const unsigned short* __restrict__ xnbf,
                                                    const unsigned short* __restrict__ pbf,
                                                    const unsigned short* __restrict__ pbfT,
                                                    unsigned short* __restrict__ pbm) {
    __shared__ __align__(16) unsigned short K_lds[2][2][64 * 128];  // [kh][buf] 64KB
    __shared__ __align__(16) unsigned short V_lds[2][2][128 * 64];  // 64KB
    __shared__ __align__(16) unsigned short P_lds[4][32 * 64];      // 16KB
    const int tid = threadIdx.x;
    const int w = tid >> 6, l = tid & 63, l15 = l & 15, lh = l >> 4;
    const int qg = w & 1, kh = w >> 1;
    const int q0 = blockIdx.x * 64;
    const int qb = q0 + qg * 32;
    short8b Xf[2][4];
    #pragma unroll
    for (int g = 0; g < 2; ++g)
        #pragma unroll
        for (int kk = 0; kk < 4; ++kk)
            Xf[g][kk] = *(const short8b*)(xnbf + (size_t)(qb + g*16 + l15)*D_ + kk*32 + lh*8);

    const int half = tid >> 7;      // == kh for this thread's wave
    const int ht = tid & 127;

    #define STAGE_KV(buf, itt)                                                       \
        { const int t0s = half * 1024 + (itt) * 64;                                  \
          unsigned short* KB_ = K_lds[half][buf];                                    \
          unsigned short* VB_ = V_lds[half][buf];                                    \
          _Pragma("unroll")                                                          \
          for (int i = 0; i < 8; ++i) {                                              \
            const int s = ht + 128*i;                                                \
            { const int key = s >> 4, chs = s & 15;                                  \
              gl16(pbf + (size_t)(t0s + key)*128 + (chs ^ (key & 7))*8, KB_ + s*8); }\
            { const int d = s >> 3, c2 = s & 7;                                      \
              gl16(pbfT + (size_t)d*BN_ + t0s + (c2 ^ (d & 7))*8, VB_ + s*8); }      \
          } }

    STAGE_KV(0, 0)
    float lsum[2] = {0.f, 0.f};
    f32x4 acc[2][8] = {};
    asm volatile("s_waitcnt vmcnt(0)");
    __syncthreads();
    int cur = 0;
    for (int it = 0; it < 16; ++it) {
        if (it < 15) STAGE_KV(cur ^ 1, it + 1)
        const unsigned short* KB = K_lds[kh][cur];
        const unsigned short* VB = V_lds[kh][cur];
        // QK^T (swapped): S[g][kt] = C[key][q]
        f32x4 S[2][4] = {};
        #pragma unroll
        for (int kk = 0; kk < 4; ++kk) {
            #pragma unroll
            for (int kt = 0; kt < 4; ++kt) {
                const int key = kt*16 + l15;
                short8b Kf = *(const short8b*)(KB + key*128 + ((kk*4 + lh) ^ (key & 7))*8);
                S[0][kt] = __builtin_amdgcn_mfma_f32_16x16x32_bf16(Kf, Xf[0][kk], S[0][kt], 0, 0, 0);
                S[1][kt] = __builtin_amdgcn_mfma_f32_16x16x32_bf16(Kf, Xf[1][kk], S[1][kt], 0, 0, 0);
            }
        }
        // p = exp(sim - 1), pack to wave-local P
        unsigned short* PW = P_lds[w];
        #pragma unroll
        for (int g = 0; g < 2; ++g)
            #pragma unroll
            for (int kt = 0; kt < 4; ++kt) {
                us4 pk;
                #pragma unroll
                for (int jr = 0; jr < 4; ++jr) {
                    const float p = exp2f((S[g][kt][jr] - 1.0f) * LOG2E);
                    lsum[g] += p;
                    pk[jr] = f2bf(p);
                }
                const int chunk = (kt*2 + (lh >> 1)) ^ (l15 & 7);
                *(us4*)&PW[(g*16 + l15)*64 + chunk*8 + (lh & 1)*4] = pk;
            }
        // PV
        short8b Pf[2][2];
        #pragma unroll
        for (int g = 0; g < 2; ++g)
            #pragma unroll
            for (int kkk = 0; kkk < 2; ++kkk)
                Pf[g][kkk] = *(const short8b*)&PW[(g*16 + l15)*64 + ((kkk*4 + lh) ^ (l15 & 7))*8];
        #pragma unroll
        for (int nb = 0; nb < 8; ++nb) {
            const int d = nb*16 + l15;
            short8b Vf0 = *(const short8b*)(VB + d*64 + ((lh)     ^ (d & 7))*8);
            short8b Vf1 = *(const short8b*)(VB + d*64 + ((4 + lh) ^ (d & 7))*8);
            acc[0][nb] = __builtin_amdgcn_mfma_f32_16x16x32_bf16(Pf[0][0], Vf0, acc[0][nb], 0, 0, 0);
            acc[0][nb] = __builtin_amdgcn_mfma_f32_16x16x32_bf16(Pf[0][1], Vf1, acc[0][nb], 0, 0, 0);
            acc[1][nb] = __builtin_amdgcn_mfma_f32_16x16x32_bf16(Pf[1][0], Vf0, acc[1][nb], 0, 0, 0);
            acc[1][nb] = __builtin_amdgcn_mfma_f32_16x16x32_bf16(Pf[1][1], Vf1, acc[1][nb], 0, 0, 0);
        }
        asm volatile("s_waitcnt vmcnt(0)");
        __syncthreads();
        cur ^= 1;
    }
    #pragma unroll
    for (int g = 0; g < 2; ++g) {
        lsum[g] += __shfl_xor(lsum[g], 16);
        lsum[g] += __shfl_xor(lsum[g], 32);
    }
    // combine key-halves
    float* Obuf = (float*)&K_lds[0][0][0];   // [64][132] fp32
    float* lbuf = (float*)&V_lds[0][0][0];   // 64 floats
    if (kh == 1) {
        #pragma unroll
        for (int g = 0; g < 2; ++g)
            #pragma unroll
            for (int nb = 0; nb < 8; ++nb)
                #pragma unroll
                for (int jr = 0; jr < 4; ++jr) {
                    const int row = qg*32 + g*16 + lh*4 + jr;
                    Obuf[row*132 + nb*16 + l15] = acc[g][nb][jr];
                }
        if (l < 16) { lbuf[qg*32 + l15] = lsum[0]; lbuf[qg*32 + 16 + l15] = lsum[1]; }
    }
    __syncthreads();
    if (kh == 0) {
        #pragma unroll
        for (int g = 0; g < 2; ++g) {
            const float inv = 1.0f / (lsum[g] + lbuf[qg*32 + g*16 + l15]);
            #pragma unroll
            for (int jr = 0; jr < 4; ++jr) {
                const float rl = __shfl(inv, lh*4 + jr, 64);
                #pragma unroll
                for (int nb = 0; nb < 8; ++nb) {
                    const int row = qg*32 + g*16 + lh*4 + jr;
                    const float o = (acc[g][nb][jr] + Obuf[row*132 + nb*16 + l15]) * rl;
                    pbm[(size_t)(q0 + row)*D_ + nb*16 + l15] = f2bf(o);
                }
            }
        }
    }
}

// ---------------------------------------------------------------------------
// K_res: out2 = x @ w_p + b_p, via xnbf*||x||. 256 blocks x 256 thr, 64 rows.
// ---------------------------------------------------------------------------
__global__ __launch_bounds__(256) void k_res_mfma(const unsigned short* __restrict__ xnbf,
                                                  const float* __restrict__ xnorm,
                                                  const unsigned short* __restrict__ wpT,
                                                  const float* __restrict__ bp,
                                                  float* __restrict__ out2) {
    __shared__ __align__(16) unsigned short XA[64 * 128];
    __shared__ __align__(16) unsigned short WB[128 * 128];
    const int tid = threadIdx.x;
    const int w = tid >> 6, l = tid & 63, l15 = l & 15, lh = l >> 4;
    const int r0 = blockIdx.x * 64;
    #pragma unroll
    for (int i = 0; i < 4; ++i) {      // 64 rows x 16 chunks = 1024 (was i<2: BUG)
        const int s = tid + 256*i;
        const int r = s >> 4, chs = s & 15;
        gl16(xnbf + (size_t)(r0 + r)*128 + (chs ^ (r & 7))*8, XA + s*8);
    }
    #pragma unroll
    for (int i = 0; i < 8; ++i) {
        const int s = tid + 256*i;
        const int r = s >> 4, chs = s & 15;
        gl16(wpT + (size_t)r*128 + (chs ^ (r & 7))*8, WB + s*8);
    }
    asm volatile("s_waitcnt vmcnt(0)");
    __syncthreads();
    const int rb = w * 16;
    f32x4 acc[8] = {};
    #pragma unroll
    for (int kc = 0; kc < 4; ++kc) {
        const int r = rb + l15;
        short8b Af = *(const short8b*)(XA + r*128 + ((kc*4 + lh) ^ (r & 7))*8);
        #pragma unroll
        for (int cb = 0; cb < 8; ++cb) {
            const int c = cb*16 + l15;
            short8b Bf = *(const short8b*)(WB + c*128 + ((kc*4 + lh) ^ (c & 7))*8);
            acc[cb] = __builtin_amdgcn_mfma_f32_16x16x32_bf16(Af, Bf, acc[cb], 0, 0, 0);
        }
    }
    #pragma unroll
    for (int jr = 0; jr < 4; ++jr) {
        const int r = r0 + rb + lh*4 + jr;
        const float xn = xnorm[r];
        #pragma unroll
        for (int cb = 0; cb < 8; ++cb) {
            const int c = cb*16 + l15;
            out2[(size_t)r*128 + c] = xn * acc[cb][jr] + bp[c];
        }
    }
}

// ---------------------------------------------------------------------------
// K5: out0 = gelu(pbm @ w_d1 + b1) @ w_d2 + b2 + res. 256 blocks x 256 thr.
// ---------------------------------------------------------------------------
__global__ __launch_bounds__(256) void k5_mlp_mfma(const unsigned short* __restrict__ pbm,
                                                   const unsigned short* __restrict__ wd1T,
                                                   const float* __restrict__ b1,
                                                   const unsigned short* __restrict__ wd2T,
                                                   const float* __restrict__ b2,
                                                   const float* __restrict__ res,
                                                   float* __restrict__ out0) {
    __shared__ __align__(16) unsigned short PA[64 * 128];
    __shared__ __align__(16) unsigned short W1B[128 * 128];
    __shared__ __align__(16) unsigned short W2B[128 * 128];
    __shared__ __align__(16) unsigned short T1[64 * 128];  // [r][h], byte ^ ((r&7)<<4)
    const int tid = threadIdx.x;
    const int w = tid >> 6, l = tid & 63, l15 = l & 15, lh = l >> 4;
    const int r0 = blockIdx.x * 64;
    #pragma unroll
    for (int i = 0; i < 4; ++i) {      // 64 rows x 16 chunks = 1024 (was i<2: BUG)
        const int s = tid + 256*i;
        const int r = s >> 4, chs = s & 15;
        gl16(pbm + (size_t)(r0 + r)*128 + (chs ^ (r & 7))*8, PA + s*8);
    }
    #pragma unroll
    for (int i = 0; i < 8; ++i) {
        const int s = tid + 256*i;
        const int r = s >> 4, chs = s & 15;
        gl16(wd1T + (size_t)r*128 + (chs ^ (r & 7))*8, W1B + s*8);
        gl16(wd2T + (size_t)r*128 + (chs ^ (r & 7))*8, W2B + s*8);
    }
    asm volatile("s_waitcnt vmcnt(0)");
    __syncthreads();
    const int rb = w * 16;
    f32x4 acc1[8] = {};
    #pragma unroll
    for (int kc = 0; kc < 4; ++kc) {
        const int r = rb + l15;
        short8b Af = *(const short8b*)(PA + r*128 + ((kc*4 + lh) ^ (r & 7))*8);
        #pragma unroll
        for (int hb = 0; hb < 8; ++hb) {
            const int h = hb*16 + l15;
            short8b Bf = *(const short8b*)(W1B + h*128 + ((kc*4 + lh) ^ (h & 7))*8);
            acc1[hb] = __builtin_amdgcn_mfma_f32_16x16x32_bf16(Af, Bf, acc1[hb], 0, 0, 0);
        }
    }
    // gelu + bias -> T1[r][h] (wave-local rows)
    #pragma unroll
    for (int hb = 0; hb < 8; ++hb) {
        const int h = hb*16 + l15;
        const float bb = b1[h];
        #pragma unroll
        for (int jr = 0; jr < 4; ++jr) {
            const int r = rb + lh*4 + jr;
            const float v = gelu_exact(acc1[hb][jr] + bb);
            *(unsigned short*)((char*)T1 + r*256 + ((h*2) ^ ((r & 7) << 4))) = f2bf(v);
        }
    }
    __syncthreads();
    f32x4 acc2[8] = {};
    #pragma unroll
    for (int kc = 0; kc < 4; ++kc) {
        const int r = rb + l15;
        short8b Af = *(const short8b*)((char*)T1 + r*256 + ((kc*64 + lh*16) ^ ((r & 7) << 4)));
        #pragma unroll
        for (int cb = 0; cb < 8; ++cb) {
            const int c = cb*16 + l15;
            short8b Bf = *(const short8b*)(W2B + c*128 + ((kc*4 + lh) ^ (c & 7))*8);
            acc2[cb] = __builtin_amdgcn_mfma_f32_16x16x32_bf16(Af, Bf, acc2[cb], 0, 0, 0);
        }
    }
    #pragma unroll
    for (int cb = 0; cb < 8; ++cb) {
        const int c = cb*16 + l15;
        const float bb = b2[c];
        #pragma unroll
        for (int jr = 0; jr < 4; ++jr) {
            const int r = r0 + rb + lh*4 + jr;
            out0[(size_t)r*128 + c] = acc2[cb][jr] + bb + res[(size_t)r*128 + c];
        }
    }
}

// ---------------------------------------------------------------------------
extern "C" void kernel_launch(void* const* d_in, const int* in_sizes, int n_in,
                              void* d_out, int out_size, void* d_ws, size_t ws_size,
                              hipStream_t stream) {
    const float* x    = (const float*)d_in[0];
    const float* w_n1 = (const float*)d_in[2];
    const float* b_n1 = (const float*)d_in[3];
    const float* w_n2 = (const float*)d_in[4];
    const float* b_n2 = (const float*)d_in[5];
    const float* w_d1 = (const float*)d_in[6];
    const float* b_d1 = (const float*)d_in[7];
    const float* w_d2 = (const float*)d_in[8];
    const float* b_d2 = (const float*)d_in[9];
    const float* w_p  = (const float*)d_in[10];
    const float* b_p  = (const float*)d_in[11];

    float* out0 = (float*)d_out;                    // [16384,128]
    float* out1 = out0 + (size_t)BS_ * D_;          // proto [2048,128]
    float* out2 = out1 + (size_t)BN_ * D_;          // res   [16384,128]

    char* ws = (char*)d_ws;
    unsigned short* xnbf = (unsigned short*)ws;                         // 4MB normalized bf16 x
    unsigned short* xT   = (unsigned short*)(ws + (4u << 20));          // 4MB [16][128][1024]
    unsigned short* pbm  = xT;                                          // overlay: prompt bf16 (after k12 consumes xT)
    float* xnorm         = (float*)(ws + (8u << 20));                   // 64KB
    unsigned short* w1T  = (unsigned short*)(ws + (8u << 20) + (64u << 10)); // 256KB
    unsigned short* w2T  = w1T + 128 * 1024;
    unsigned short* wpT  = w2T + 128 * 128;
    unsigned short* wd1T = wpT + 128 * 128;
    unsigned short* wd2T = wd1T + 128 * 128;
    unsigned short* pbf  = wd2T + 128 * 128;        // [2048][128] normalized
    unsigned short* pbfT = pbf + (size_t)BN_ * D_;  // [128][2048] unnormalized

    hipLaunchKernelGGL(k0a_xprep,   dim3(256), dim3(256), 0, stream, x, xnbf, xT, xnorm);
    hipLaunchKernelGGL(k0b_wprep,   dim3(48),  dim3(256), 0, stream, w_n1, w_n2, w_p, w_d1, w_d2,
                       w1T, w2T, wpT, wd1T, wd2T);
    hipLaunchKernelGGL(k12_proto,   dim3(16),  dim3(512), 0, stream, xT, w1T, b_n1, w2T, b_n2,
                       out1, pbf, pbfT);
    hipLaunchKernelGGL(k_res_mfma,  dim3(256), dim3(256), 0, stream, xnbf, xnorm, wpT, b_p, out2);
    hipLaunchKernelGGL(k4_attn_mfma,dim3(256), dim3(256), 0, stream, xnbf, pbf, pbfT, pbm);
    hipLaunchKernelGGL(k5_mlp_mfma, dim3(256), dim3(256), 0, stream, pbm, wd1T, b_d1, wd2T, b_d2,
                       out2, out0);
}

// Round 5
// 177.069 us; speedup vs baseline: 2.8481x; 1.0002x over previous
//
#include <hip/hip_runtime.h>
#include <math.h>

#define B_ 16
#define S_ 1024
#define D_ 128
#define N_ 128
#define BS_ (B_*S_)   // 16384 query rows
#define BN_ (B_*N_)   // 2048 prototype rows
#define LOG2E 1.442695040888963f

typedef __attribute__((ext_vector_type(8))) short short8b;
typedef __attribute__((ext_vector_type(4))) float f32x4;
typedef __attribute__((ext_vector_type(16))) float f32x16;
typedef __attribute__((ext_vector_type(4))) unsigned short us4;
typedef __attribute__((ext_vector_type(4))) unsigned int u32x4;

__device__ __forceinline__ float gelu_exact(float x) {
    return 0.5f * x * (1.0f + erff(x * 0.70710678118654752440f));
}

// RNE float->bf16
__device__ __forceinline__ unsigned short f2bf(float f) {
    unsigned u = __builtin_bit_cast(unsigned, f);
    unsigned r = (u + 0x7FFFu + ((u >> 16) & 1u)) >> 16;
    return (unsigned short)r;
}
__device__ __forceinline__ unsigned int pk2(float lo, float hi) {
    return (unsigned)f2bf(lo) | ((unsigned)f2bf(hi) << 16);
}

__device__ __forceinline__ void gl16(const void* g, void* l) {
    __builtin_amdgcn_global_load_lds((const __attribute__((address_space(1))) unsigned int*)g,
                                     (__attribute__((address_space(3))) unsigned int*)l,
                                     16, 0, 0);
}

// MFMA conventions (HW-verified R1/R2):
//  16x16x32: mfma(Af,Bf,C): C[i][j]=sum_c A[i][c]B[j][c]; A/B: lane(l15,lh) row=l15,
//            c=kc*32+lh*8+j; C/D: lane(l15,lh) reg jr = C[4*lh+jr][l15].
//  32x32x16: A/B: lane(l31,hi) row=l31, c=hi*8+j (K=16); C/D: col=lane&31,
//            row=(r&3)+8*(r>>2)+4*hi (r=0..15)  [guide m74/m101].
// Staged tiles: linear LDS dest (global_load_lds rule), inverse-swizzled GLOBAL
// source, same XOR on reads.

// ---------------------------------------------------------------------------
// K0a: x prep: xnbf = bf16(x/||x||); xT[b][d][s] = bf16(x) transposed; xnorm.
// ---------------------------------------------------------------------------
__global__ __launch_bounds__(256) void k0a_xprep(const float* __restrict__ x,
                                                 unsigned short* __restrict__ xnbf,
                                                 unsigned short* __restrict__ xT,
                                                 float* __restrict__ xnorm) {
    __shared__ __align__(16) unsigned int T2[128 * 32];
    const int b  = blockIdx.x >> 4;
    const int s0 = (blockIdx.x & 15) * 64;
    const int t  = threadIdx.x;
    const int rp = t >> 3;
    const int q  = t & 7;
    const int row0 = s0 + 2 * rp;
    const float* p0 = x + ((size_t)b * S_ + row0) * D_ + q * 16;
    const float* p1 = p0 + D_;
    f32x4 a[4], c[4];
    #pragma unroll
    for (int i = 0; i < 4; ++i) { a[i] = ((const f32x4*)p0)[i]; c[i] = ((const f32x4*)p1)[i]; }
    float sa = 0.f, sc = 0.f;
    #pragma unroll
    for (int i = 0; i < 4; ++i)
        #pragma unroll
        for (int j = 0; j < 4; ++j) { sa += a[i][j]*a[i][j]; sc += c[i][j]*c[i][j]; }
    sa += __shfl_xor(sa, 1); sa += __shfl_xor(sa, 2); sa += __shfl_xor(sa, 4);
    sc += __shfl_xor(sc, 1); sc += __shfl_xor(sc, 2); sc += __shfl_xor(sc, 4);
    const float na = sqrtf(sa), nc = sqrtf(sc);
    if (q == 0) {
        xnorm[(size_t)b*S_ + row0]     = na;
        xnorm[(size_t)b*S_ + row0 + 1] = nc;
    }
    const float ia = 1.0f / na, ic = 1.0f / nc;
    unsigned int pk[8];
    #pragma unroll
    for (int i = 0; i < 4; ++i) {
        pk[2*i]   = pk2(a[i][0]*ia, a[i][1]*ia);
        pk[2*i+1] = pk2(a[i][2]*ia, a[i][3]*ia);
    }
    *(u32x4*)(xnbf + ((size_t)b*S_ + row0)*D_ + q*16)     = *(u32x4*)&pk[0];
    *(u32x4*)(xnbf + ((size_t)b*S_ + row0)*D_ + q*16 + 8) = *(u32x4*)&pk[4];
    #pragma unroll
    for (int i = 0; i < 4; ++i) {
        pk[2*i]   = pk2(c[i][0]*ic, c[i][1]*ic);
        pk[2*i+1] = pk2(c[i][2]*ic, c[i][3]*ic);
    }
    *(u32x4*)(xnbf + ((size_t)b*S_ + row0 + 1)*D_ + q*16)     = *(u32x4*)&pk[0];
    *(u32x4*)(xnbf + ((size_t)b*S_ + row0 + 1)*D_ + q*16 + 8) = *(u32x4*)&pk[4];
    #pragma unroll
    for (int i = 0; i < 4; ++i)
        #pragma unroll
        for (int j = 0; j < 4; ++j) {
            const int d = q*16 + i*4 + j;
            *(unsigned int*)((char*)T2 + d*128 + ((rp*4) ^ (((d>>3)&7)<<4))) =
                pk2(a[i][j], c[i][j]);
        }
    __syncthreads();
    const int d  = t >> 1;
    const int hf = t & 1;
    unsigned short* dst = xT + ((size_t)(b*128 + d))*1024 + s0 + hf*32;
    #pragma unroll
    for (int cI = 0; cI < 4; ++cI) {
        const int sp0 = hf*16 + cI*4;
        u32x4 v = *(u32x4*)((char*)T2 + d*128 + ((sp0*4) ^ (((d>>3)&7)<<4)));
        *(u32x4*)(dst + cI*8) = v;
    }
}

// ---------------------------------------------------------------------------
// K0b: weight transposes to bf16.
// ---------------------------------------------------------------------------
__global__ __launch_bounds__(256) void k0b_wprep(const float* __restrict__ w1,
                                                 const float* __restrict__ w2,
                                                 const float* __restrict__ wp,
                                                 const float* __restrict__ wd1,
                                                 const float* __restrict__ wd2,
                                                 unsigned short* __restrict__ w1T,
                                                 unsigned short* __restrict__ w2T,
                                                 unsigned short* __restrict__ wpT,
                                                 unsigned short* __restrict__ wd1T,
                                                 unsigned short* __restrict__ wd2T) {
    __shared__ __align__(16) unsigned int T2[64 * 32];
    const int bi = blockIdx.x;
    const float* src; unsigned short* dst; int R, r0, c0;
    if (bi < 32) {
        src = w1; dst = w1T; R = 1024;
        r0 = (bi >> 1) * 64; c0 = (bi & 1) * 64;
    } else {
        const int k = (bi - 32) >> 2, qd = (bi - 32) & 3;
        const float* ss[4] = {w2, wp, wd1, wd2};
        unsigned short* dd[4] = {w2T, wpT, wd1T, wd2T};
        src = ss[k]; dst = dd[k]; R = 128;
        r0 = (qd >> 1) * 64; c0 = (qd & 1) * 64;
    }
    const int t = threadIdx.x;
    const int rp = t >> 3, q = t & 7;
    const float* p0 = src + (size_t)(r0 + 2*rp) * 128 + c0 + q*8;
    const float* p1 = p0 + 128;
    f32x4 a0 = ((const f32x4*)p0)[0], a1 = ((const f32x4*)p0)[1];
    f32x4 b0 = ((const f32x4*)p1)[0], b1 = ((const f32x4*)p1)[1];
    #pragma unroll
    for (int j = 0; j < 4; ++j) {
        int cc = q*8 + j;
        *(unsigned int*)((char*)T2 + cc*128 + ((rp*4) ^ (((cc>>3)&7)<<4))) = pk2(a0[j], b0[j]);
        cc = q*8 + 4 + j;
        *(unsigned int*)((char*)T2 + cc*128 + ((rp*4) ^ (((cc>>3)&7)<<4))) = pk2(a1[j], b1[j]);
    }
    __syncthreads();
    const int cI = t >> 2, qt = t & 3;
    unsigned short* od = dst + (size_t)(c0 + cI) * R + r0 + qt*16;
    #pragma unroll
    for (int u = 0; u < 2; ++u) {
        const int sp0 = qt*8 + u*4;
        u32x4 v = *(u32x4*)((char*)T2 + cI*128 + ((sp0*4) ^ (((cI>>3)&7)<<4)));
        *(u32x4*)(od + u*8) = v;
    }
}

// ---------------------------------------------------------------------------
// K12: fused proto pipeline (unchanged, known-good).
// ---------------------------------------------------------------------------
__global__ __launch_bounds__(512) void k12_proto(const unsigned short* __restrict__ xT,
                                                 const unsigned short* __restrict__ w1T,
                                                 const float* __restrict__ b_n1,
                                                 const unsigned short* __restrict__ w2T,
                                                 const float* __restrict__ b_n2,
                                                 float* __restrict__ out1,
                                                 unsigned short* __restrict__ pbf,
                                                 unsigned short* __restrict__ pbfT) {
    __shared__ __align__(16) unsigned short pool[2][2][128 * 64];
    __shared__ __align__(16) unsigned short GT[128][136];
    __shared__ float nrm[128][2];
    const int b = blockIdx.x;
    const int tid = threadIdx.x;
    const int w = tid >> 6, l = tid & 63, l15 = l & 15, lh = l >> 4;
    const int mb = (w & 3) * 32;
    const int db = (w >> 2) * 64;

    f32x4 acc[2][4] = {};

    #define STAGE_A(buf, itt)                                                        \
        { _Pragma("unroll")                                                          \
          for (int i = 0; i < 2; ++i) {                                              \
            const int s = tid + 512*i;                                               \
            const int r = s >> 3, chs = s & 7;                                       \
            gl16(w1T + (size_t)r*1024 + (itt)*64 + (chs ^ (r & 7))*8,                \
                 &pool[buf][0][s*8]);                                                \
            gl16(xT + ((size_t)(b*128 + r))*1024 + (itt)*64 + (chs ^ (r & 7))*8,     \
                 &pool[buf][1][s*8]);                                                \
          } }

    STAGE_A(0, 0)
    asm volatile("s_waitcnt vmcnt(0)");
    __syncthreads();
    int cur = 0;
    for (int it = 0; it < 16; ++it) {
        if (it < 15) {
            STAGE_A(cur ^ 1, it + 1)
        } else {
            #pragma unroll
            for (int i = 0; i < 4; ++i) {
                const int s = tid + 512*i;
                const int r = s >> 4, chs = s & 15;
                gl16(w2T + (size_t)r*128 + (chs ^ (r & 7))*8,
                     ((unsigned short*)pool[0]) + s*8);
            }
        }
        const unsigned short* WA = pool[cur][0];
        const unsigned short* XA = pool[cur][1];
        #pragma unroll
        for (int kc = 0; kc < 2; ++kc) {
            short8b Af[2], Bf[4];
            #pragma unroll
            for (int mt = 0; mt < 2; ++mt) {
                const int m = mb + mt*16 + l15;
                Af[mt] = *(const short8b*)(WA + m*64 + ((kc*4 + lh) ^ (m & 7))*8);
            }
            #pragma unroll
            for (int dt = 0; dt < 4; ++dt) {
                const int d = db + dt*16 + l15;
                Bf[dt] = *(const short8b*)(XA + d*64 + ((kc*4 + lh) ^ (d & 7))*8);
            }
            #pragma unroll
            for (int mt = 0; mt < 2; ++mt)
                #pragma unroll
                for (int dt = 0; dt < 4; ++dt)
                    acc[mt][dt] = __builtin_amdgcn_mfma_f32_16x16x32_bf16(Af[mt], Bf[dt], acc[mt][dt], 0, 0, 0);
        }
        asm volatile("s_waitcnt vmcnt(0)");
        __syncthreads();
        cur ^= 1;
    }
    #pragma unroll
    for (int mt = 0; mt < 2; ++mt)
        #pragma unroll
        for (int dt = 0; dt < 4; ++dt)
            #pragma unroll
            for (int u = 0; u < 2; ++u) {
                const int m = mb + mt*16 + lh*4 + 2*u;
                const int d = db + dt*16 + l15;
                const float v0 = gelu_exact(acc[mt][dt][2*u]   + b_n1[m]);
                const float v1 = gelu_exact(acc[mt][dt][2*u+1] + b_n1[m+1]);
                *(unsigned int*)((char*)&GT[0][0] + d*272 + m*2) = pk2(v0, v1);
            }
    __syncthreads();
    const unsigned short* W2 = (const unsigned short*)pool[0];
    f32x4 acc2[2][4] = {};
    #pragma unroll
    for (int kc = 0; kc < 4; ++kc) {
        short8b Af[2], Bf[4];
        #pragma unroll
        for (int nt = 0; nt < 2; ++nt) {
            const int n = mb + nt*16 + l15;
            Af[nt] = *(const short8b*)(W2 + n*128 + ((kc*4 + lh) ^ (n & 7))*8);
        }
        #pragma unroll
        for (int dt = 0; dt < 4; ++dt) {
            const int d = db + dt*16 + l15;
            Bf[dt] = *(const short8b*)((char*)&GT[0][0] + d*272 + kc*64 + lh*16);
        }
        #pragma unroll
        for (int nt = 0; nt < 2; ++nt)
            #pragma unroll
            for (int dt = 0; dt < 4; ++dt)
                acc2[nt][dt] = __builtin_amdgcn_mfma_f32_16x16x32_bf16(Af[nt], Bf[dt], acc2[nt][dt], 0, 0, 0);
    }
    #pragma unroll
    for (int nt = 0; nt < 2; ++nt) {
        #pragma unroll
        for (int jr = 0; jr < 4; ++jr) {
            const int n = mb + nt*16 + lh*4 + jr;
            const float bb = b_n2[n];
            float ps = 0.f;
            #pragma unroll
            for (int dt = 0; dt < 4; ++dt) {
                const int d = db + dt*16 + l15;
                const float v = acc2[nt][dt][jr] + bb;
                acc2[nt][dt][jr] = v;
                out1[((size_t)(b*128 + n))*128 + d] = v;
                ps += v * v;
            }
            ps += __shfl_xor(ps, 1); ps += __shfl_xor(ps, 2);
            ps += __shfl_xor(ps, 4); ps += __shfl_xor(ps, 8);
            if (l15 == 0) nrm[n][w >> 2] = ps;
        }
    }
    __syncthreads();
    unsigned short* TP = (unsigned short*)pool[1];
    #pragma unroll
    for (int nt = 0; nt < 2; ++nt)
        #pragma unroll
        for (int jr = 0; jr < 4; ++jr) {
            const int n = mb + nt*16 + lh*4 + jr;
            const float pin = 1.0f / sqrtf(nrm[n][0] + nrm[n][1]);
            #pragma unroll
            for (int dt = 0; dt < 4; ++dt) {
                const int d = db + dt*16 + l15;
                pbf[((size_t)(b*128 + n))*128 + d] = f2bf(acc2[nt][dt][jr] * pin);
            }
        }
    #pragma unroll
    for (int nt = 0; nt < 2; ++nt)
        #pragma unroll
        for (int dt = 0; dt < 4; ++dt)
            #pragma unroll
            for (int u = 0; u < 2; ++u) {
                const int n0 = mb + nt*16 + lh*4 + 2*u;
                const int d = db + dt*16 + l15;
                *(unsigned int*)((char*)TP + d*256 + ((n0*2) ^ ((d & 7) << 4))) =
                    pk2(acc2[nt][dt][2*u], acc2[nt][dt][2*u+1]);
            }
    __syncthreads();
    if (tid < 256) {
        const int d = tid >> 1, hf = tid & 1;
        #pragma unroll
        for (int cI = 0; cI < 8; ++cI) {
            short8b v = *(const short8b*)((char*)TP + d*256 + ((hf*128 + cI*16) ^ ((d & 7) << 4)));
            *(short8b*)(pbfT + (size_t)d*BN_ + b*128 + hf*64 + cI*8) = v;
        }
    }
}

// ---------------------------------------------------------------------------
// K4a: cosine attention, 32x32x16 MFMA, in-register P (permlane32_swap).
// 512 blocks x 256 thr (4 waves). Block = 64 q x 1024-key half.
// Waves (qg,kq): qg = w&1 (32 q), kq = w>>1 (tile parity). 16 tiles of 64 keys;
// wave kq computes tiles with g&1==kq. Shared K/V dbuf (64 KB) -> 2 blocks/CU.
// K LDS [64 r][16 ch]: ch' = ch ^ (r&15); V LDS [128 d][8 ch]: ch' = ch ^ (d&7)
// (bank = f(ch') only -> conflict-free b128 reads).
// Partial O (fp32) + l per half -> k4b combines.
// ---------------------------------------------------------------------------
__global__ __launch_bounds__(256, 2) void k4a_attn(const unsigned short* __restrict__ xnbf,
                                                   const unsigned short* __restrict__ pbf,
                                                   const unsigned short* __restrict__ pbfT,
                                                   float* __restrict__ Op0,
                                                   float* __restrict__ Op1,
                                                   float* __restrict__ lpart) {
    __shared__ __align__(16) unsigned short Kb[2][64 * 128];   // 32 KB
    __shared__ __align__(16) unsigned short Vb[2][128 * 64];   // 32 KB
    const int tid = threadIdx.x;
    const int w = tid >> 6, l = tid & 63;
    const int l31 = l & 31, hi = l >> 5;
    const int qg = w & 1, kq = w >> 1;
    const int qblk = blockIdx.x >> 1, half = blockIdx.x & 1;
    const int qb = qblk * 64 + qg * 32;
    float* __restrict__ Opart = half ? Op1 : Op0;

    // X B-fragments resident: lane l31 = q row, c = hi*8+j per 16-d chunk kc
    short8b Xf[8];
    #pragma unroll
    for (int kc = 0; kc < 8; ++kc)
        Xf[kc] = *(const short8b*)(xnbf + (size_t)(qb + l31) * D_ + kc * 16 + hi * 8);

    f32x16 acc[4] = {};
    float lsum = 0.f;

    #define STG(buf, g)  {                                                    \
        const int t0s = half * 1024 + (g) * 64;                               \
        _Pragma("unroll")                                                     \
        for (int i = 0; i < 4; ++i) {                                         \
            const int sK = tid + 256 * i;                                     \
            const int rK = sK >> 4, cK = (sK & 15) ^ (rK & 15);               \
            gl16(pbf + (size_t)(t0s + rK) * D_ + cK * 8, Kb[buf] + sK * 8);   \
            const int dV = sK >> 3, cV = (sK & 7) ^ (dV & 7);                 \
            gl16(pbfT + (size_t)dV * BN_ + t0s + cV * 8, Vb[buf] + sK * 8);   \
        } }

    STG(0, 0)
    __syncthreads();
    for (int g = 0; g < 16; ++g) {
        if (g < 15) STG((g + 1) & 1, g + 1)
        if (kq == (g & 1)) {
            const unsigned short* KB = Kb[g & 1];
            const unsigned short* VB = Vb[g & 1];
            // QK^T: S[kt][r] = sim[key][q=l31], key = kt*32 + (r&3)+8*(r>>2)+4*hi
            f32x16 S[2] = {};
            #pragma unroll
            for (int kc = 0; kc < 8; ++kc) {
                const int cs = ((kc * 2 + hi) ^ (l31 & 15)) * 8;
                short8b K0 = *(const short8b*)(KB + l31 * 128 + cs);
                short8b K1 = *(const short8b*)(KB + (32 + l31) * 128 + cs);
                S[0] = __builtin_amdgcn_mfma_f32_32x32x16_bf16(K0, Xf[kc], S[0], 0, 0, 0);
                S[1] = __builtin_amdgcn_mfma_f32_32x32x16_bf16(K1, Xf[kc], S[1], 0, 0, 0);
            }
            // exp(sim-1), pack to bf16, permlane-redistribute -> PV A-frags
            short8b Pf[4];
            #pragma unroll
            for (int kt = 0; kt < 2; ++kt) {
                float p[16];
                #pragma unroll
                for (int r = 0; r < 16; ++r) {
                    p[r] = exp2f((S[kt][r] - 1.0f) * LOG2E);
                    lsum += p[r];
                }
                #pragma unroll
                for (int h = 0; h < 2; ++h) {
                    unsigned int wA0 = pk2(p[8*h+0], p[8*h+1]);
                    unsigned int wA1 = pk2(p[8*h+2], p[8*h+3]);
                    unsigned int wB0 = pk2(p[8*h+4], p[8*h+5]);
                    unsigned int wB1 = pk2(p[8*h+6], p[8*h+7]);
                    // vdst.lo <-> vsrc.hi: wB0 -> u32[2], wA0 -> u32[0]
                    asm("v_permlane32_swap_b32 %0, %1" : "+v"(wB0), "+v"(wA0));
                    asm("v_permlane32_swap_b32 %0, %1" : "+v"(wB1), "+v"(wA1));
                    u32x4 pw; pw[0] = wA0; pw[1] = wA1; pw[2] = wB0; pw[3] = wB1;
                    Pf[kt*2 + h] = __builtin_bit_cast(short8b, pw);
                }
            }
            // PV: acc[dt] (C: col=l31=d, rows=q)
            #pragma unroll
            for (int kc2 = 0; kc2 < 4; ++kc2) {
                #pragma unroll
                for (int dt = 0; dt < 4; ++dt) {
                    const int d = dt * 32 + l31;
                    short8b Vf = *(const short8b*)(VB + d * 64 + (((kc2*2+hi) ^ (d & 7)) * 8));
                    acc[dt] = __builtin_amdgcn_mfma_f32_32x32x16_bf16(Pf[kc2], Vf, acc[dt], 0, 0, 0);
                }
            }
        }
        __syncthreads();
    }
    // lsum: lane l31 = q (from S-phase); fold hi halves
    lsum += __shfl_xor(lsum, 32);

    // combine kq pair through LDS (reuse Kb as 32KB fp32 Obuf, Vb head as lbuf)
    float* Obuf = (float*)&Kb[0][0];
    float* lbuf = (float*)&Vb[0][0];
    if (kq == 0) {
        #pragma unroll
        for (int dt = 0; dt < 4; ++dt)
            #pragma unroll
            for (int r = 0; r < 16; ++r) {
                const int qr = (r & 3) + 8 * (r >> 2) + 4 * hi;
                Obuf[qg * 4096 + qr * 128 + dt * 32 + l31] = acc[dt][r];
            }
        if (!hi) lbuf[qg * 32 + l31] = lsum;
    }
    __syncthreads();
    if (kq == 1) {
        #pragma unroll
        for (int dt = 0; dt < 4; ++dt)
            #pragma unroll
            for (int r = 0; r < 16; ++r) {
                const int qr = (r & 3) + 8 * (r >> 2) + 4 * hi;
                const float v = acc[dt][r] + Obuf[qg * 4096 + qr * 128 + dt * 32 + l31];
                Opart[(size_t)(qb + qr) * D_ + dt * 32 + l31] = v;
            }
        if (!hi) lpart[half * BS_ + qb + l31] = lsum + lbuf[qg * 32 + l31];
    }
}

// ---------------------------------------------------------------------------
// K4b: pbm = bf16((O0+O1) / (l0+l1)).  512 blocks x 256 thr.
// ---------------------------------------------------------------------------
__global__ __launch_bounds__(256) void k4b_comb(const float* __restrict__ Op0,
                                                const float* __restrict__ Op1,
                                                const float* __restrict__ lpart,
                                                unsigned short* __restrict__ pbm) {
    const int t = blockIdx.x * 256 + threadIdx.x;
    const int row = t >> 3, d0 = (t & 7) * 16;
    const float inv = 1.0f / (lpart[row] + lpart[BS_ + row]);
    const float* a = Op0 + (size_t)row * D_ + d0;
    const float* b = Op1 + (size_t)row * D_ + d0;
    unsigned int wo[8];
    #pragma unroll
    for (int i = 0; i < 4; ++i) {
        f32x4 va = ((const f32x4*)a)[i];
        f32x4 vb = ((const f32x4*)b)[i];
        wo[2*i]   = pk2((va[0]+vb[0])*inv, (va[1]+vb[1])*inv);
        wo[2*i+1] = pk2((va[2]+vb[2])*inv, (va[3]+vb[3])*inv);
    }
    *(u32x4*)(pbm + (size_t)row * D_ + d0)     = *(u32x4*)&wo[0];
    *(u32x4*)(pbm + (size_t)row * D_ + d0 + 8) = *(u32x4*)&wo[4];
}

// ---------------------------------------------------------------------------
// K_res: out2 = x @ w_p + b_p (unchanged).
// ---------------------------------------------------------------------------
__global__ __launch_bounds__(256) void k_res_mfma(const unsigned short* __restrict__ xnbf,
                                                  const float* __restrict__ xnorm,
                                                  const unsigned short* __restrict__ wpT,
                                                  const float* __restrict__ bp,
                                                  float* __restrict__ out2) {
    __shared__ __align__(16) unsigned short XA[64 * 128];
    __shared__ __align__(16) unsigned short WB[128 * 128];
    const int tid = threadIdx.x;
    const int w = tid >> 6, l = tid & 63, l15 = l & 15, lh = l >> 4;
    const int r0 = blockIdx.x * 64;
    #pragma unroll
    for (int i = 0; i < 4; ++i) {
        const int s = tid + 256*i;
        const int r = s >> 4, chs = s & 15;
        gl16(xnbf + (size_t)(r0 + r)*128 + (chs ^ (r & 7))*8, XA + s*8);
    }
    #pragma unroll
    for (int i = 0; i < 8; ++i) {
        const int s = tid + 256*i;
        const int r = s >> 4, chs = s & 15;
        gl16(wpT + (size_t)r*128 + (chs ^ (r & 7))*8, WB + s*8);
    }
    asm volatile("s_waitcnt vmcnt(0)");
    __syncthreads();
    const int rb = w * 16;
    f32x4 acc[8] = {};
    #pragma unroll
    for (int kc = 0; kc < 4; ++kc) {
        const int r = rb + l15;
        short8b Af = *(const short8b*)(XA + r*128 + ((kc*4 + lh) ^ (r & 7))*8);
        #pragma unroll
        for (int cb = 0; cb < 8; ++cb) {
            const int c = cb*16 + l15;
            short8b Bf = *(const short8b*)(WB + c*128 + ((kc*4 + lh) ^ (c & 7))*8);
            acc[cb] = __builtin_amdgcn_mfma_f32_16x16x32_bf16(Af, Bf, acc[cb], 0, 0, 0);
        }
    }
    #pragma unroll
    for (int jr = 0; jr < 4; ++jr) {
        const int r = r0 + rb + lh*4 + jr;
        const float xn = xnorm[r];
        #pragma unroll
        for (int cb = 0; cb < 8; ++cb) {
            const int c = cb*16 + l15;
            out2[(size_t)r*128 + c] = xn * acc[cb][jr] + bp[c];
        }
    }
}

// ---------------------------------------------------------------------------
// K5: out0 = gelu(pbm @ w_d1 + b1) @ w_d2 + b2 + res (unchanged).
// ---------------------------------------------------------------------------
__global__ __launch_bounds__(256) void k5_mlp_mfma(const unsigned short* __restrict__ pbm,
                                                   const unsigned short* __restrict__ wd1T,
                                                   const float* __restrict__ b1,
                                                   const unsigned short* __restrict__ wd2T,
                                                   const float* __restrict__ b2,
                                                   const float* __restrict__ res,
                                                   float* __restrict__ out0) {
    __shared__ __align__(16) unsigned short PA[64 * 128];
    __shared__ __align__(16) unsigned short W1B[128 * 128];
    __shared__ __align__(16) unsigned short W2B[128 * 128];
    __shared__ __align__(16) unsigned short T1[64 * 128];
    const int tid = threadIdx.x;
    const int w = tid >> 6, l = tid & 63, l15 = l & 15, lh = l >> 4;
    const int r0 = blockIdx.x * 64;
    #pragma unroll
    for (int i = 0; i < 4; ++i) {
        const int s = tid + 256*i;
        const int r = s >> 4, chs = s & 15;
        gl16(pbm + (size_t)(r0 + r)*128 + (chs ^ (r & 7))*8, PA + s*8);
    }
    #pragma unroll
    for (int i = 0; i < 8; ++i) {
        const int s = tid + 256*i;
        const int r = s >> 4, chs = s & 15;
        gl16(wd1T + (size_t)r*128 + (chs ^ (r & 7))*8, W1B + s*8);
        gl16(wd2T + (size_t)r*128 + (chs ^ (r & 7))*8, W2B + s*8);
    }
    asm volatile("s_waitcnt vmcnt(0)");
    __syncthreads();
    const int rb = w * 16;
    f32x4 acc1[8] = {};
    #pragma unroll
    for (int kc = 0; kc < 4; ++kc) {
        const int r = rb + l15;
        short8b Af = *(const short8b*)(PA + r*128 + ((kc*4 + lh) ^ (r & 7))*8);
        #pragma unroll
        for (int hb = 0; hb < 8; ++hb) {
            const int h = hb*16 + l15;
            short8b Bf = *(const short8b*)(W1B + h*128 + ((kc*4 + lh) ^ (h & 7))*8);
            acc1[hb] = __builtin_amdgcn_mfma_f32_16x16x32_bf16(Af, Bf, acc1[hb], 0, 0, 0);
        }
    }
    #pragma unroll
    for (int hb = 0; hb < 8; ++hb) {
        const int h = hb*16 + l15;
        const float bb = b1[h];
        #pragma unroll
        for (int jr = 0; jr < 4; ++jr) {
            const int r = rb + lh*4 + jr;
            const float v = gelu_exact(acc1[hb][jr] + bb);
            *(unsigned short*)((char*)T1 + r*256 + ((h*2) ^ ((r & 7) << 4))) = f2bf(v);
        }
    }
    __syncthreads();
    f32x4 acc2[8] = {};
    #pragma unroll
    for (int kc = 0; kc < 4; ++kc) {
        const int r = rb + l15;
        short8b Af = *(const short8b*)((char*)T1 + r*256 + ((kc*64 + lh*16) ^ ((r & 7) << 4)));
        #pragma unroll
        for (int cb = 0; cb < 8; ++cb) {
            const int c = cb*16 + l15;
            short8b Bf = *(const short8b*)(W2B + c*128 + ((kc*4 + lh) ^ (c & 7))*8);
            acc2[cb] = __builtin_amdgcn_mfma_f32_16x16x32_bf16(Af, Bf, acc2[cb], 0, 0, 0);
        }
    }
    #pragma unroll
    for (int cb = 0; cb < 8; ++cb) {
        const int c = cb*16 + l15;
        const float bb = b2[c];
        #pragma unroll
        for (int jr = 0; jr < 4; ++jr) {
            const int r = r0 + rb + lh*4 + jr;
            out0[(size_t)r*128 + c] = acc2[cb][jr] + bb + res[(size_t)r*128 + c];
        }
    }
}

// ---------------------------------------------------------------------------
extern "C" void kernel_launch(void* const* d_in, const int* in_sizes, int n_in,
                              void* d_out, int out_size, void* d_ws, size_t ws_size,
                              hipStream_t stream) {
    const float* x    = (const float*)d_in[0];
    const float* w_n1 = (const float*)d_in[2];
    const float* b_n1 = (const float*)d_in[3];
    const float* w_n2 = (const float*)d_in[4];
    const float* b_n2 = (const float*)d_in[5];
    const float* w_d1 = (const float*)d_in[6];
    const float* b_d1 = (const float*)d_in[7];
    const float* w_d2 = (const float*)d_in[8];
    const float* b_d2 = (const float*)d_in[9];
    const float* w_p  = (const float*)d_in[10];
    const float* b_p  = (const float*)d_in[11];

    float* out0 = (float*)d_out;                    // [16384,128] (scratch-reused as Opart0)
    float* out1 = out0 + (size_t)BS_ * D_;          // proto [2048,128]
    float* out2 = out1 + (size_t)BN_ * D_;          // res   [16384,128]

    char* ws = (char*)d_ws;
    unsigned short* xnbf = (unsigned short*)ws;                         // 4MB
    unsigned short* xT   = (unsigned short*)(ws + (4u << 20));          // 4MB
    unsigned short* pbm  = xT;                                          // overlay (xT dead after k12)
    float* xnorm         = (float*)(ws + (8u << 20));                   // 64KB
    unsigned short* w1T  = (unsigned short*)(ws + (8u << 20) + (64u << 10));
    unsigned short* w2T  = w1T + 128 * 1024;
    unsigned short* wpT  = w2T + 128 * 128;
    unsigned short* wd1T = wpT + 128 * 128;
    unsigned short* wd2T = wd1T + 128 * 128;
    unsigned short* pbf  = wd2T + 128 * 128;        // [2048][128] normalized
    unsigned short* pbfT = pbf + (size_t)BN_ * D_;  // [128][2048] unnormalized
    float* Opart0        = out0;                    // 8MB scratch (k5 overwrites last)
    float* Opart1        = (float*)(ws + (10u << 20));                  // 8MB
    float* lpart         = (float*)(ws + (18u << 20));                  // 2*64KB

    hipLaunchKernelGGL(k0a_xprep,   dim3(256), dim3(256), 0, stream, x, xnbf, xT, xnorm);
    hipLaunchKernelGGL(k0b_wprep,   dim3(48),  dim3(256), 0, stream, w_n1, w_n2, w_p, w_d1, w_d2,
                       w1T, w2T, wpT, wd1T, wd2T);
    hipLaunchKernelGGL(k12_proto,   dim3(16),  dim3(512), 0, stream, xT, w1T, b_n1, w2T, b_n2,
                       out1, pbf, pbfT);
    hipLaunchKernelGGL(k_res_mfma,  dim3(256), dim3(256), 0, stream, xnbf, xnorm, wpT, b_p, out2);
    hipLaunchKernelGGL(k4a_attn,    dim3(512), dim3(256), 0, stream, xnbf, pbf, pbfT,
                       Opart0, Opart1, lpart);
    hipLaunchKernelGGL(k4b_comb,    dim3(512), dim3(256), 0, stream, Opart0, Opart1, lpart, pbm);
    hipLaunchKernelGGL(k5_mlp_mfma, dim3(256), dim3(256), 0, stream, pbm, wd1T, b_d1, wd2T, b_d2,
                       out2, out0);
}

// Round 6
// 163.774 us; speedup vs baseline: 3.0793x; 1.0812x over previous
//
#include <hip/hip_runtime.h>
#include <math.h>

#define B_ 16
#define S_ 1024
#define D_ 128
#define N_ 128
#define BS_ (B_*S_)   // 16384 query rows
#define BN_ (B_*N_)   // 2048 prototype rows
#define LOG2E 1.442695040888963f

typedef __attribute__((ext_vector_type(8))) short short8b;
typedef __attribute__((ext_vector_type(4))) float f32x4;
typedef __attribute__((ext_vector_type(16))) float f32x16;
typedef __attribute__((ext_vector_type(4))) unsigned short us4;
typedef __attribute__((ext_vector_type(4))) unsigned int u32x4;

__device__ __forceinline__ float gelu_exact(float x) {
    return 0.5f * x * (1.0f + erff(x * 0.70710678118654752440f));
}

// RNE float->bf16
__device__ __forceinline__ unsigned short f2bf(float f) {
    unsigned u = __builtin_bit_cast(unsigned, f);
    unsigned r = (u + 0x7FFFu + ((u >> 16) & 1u)) >> 16;
    return (unsigned short)r;
}
__device__ __forceinline__ unsigned int pk2(float lo, float hi) {
    return (unsigned)f2bf(lo) | ((unsigned)f2bf(hi) << 16);
}
// HW packed cvt (RNE) — 1 inst instead of ~18
__device__ __forceinline__ unsigned int cvtpk(float lo, float hi) {
    unsigned r;
    asm("v_cvt_pk_bf16_f32 %0, %1, %2" : "=v"(r) : "v"(lo), "v"(hi));
    return r;
}
__device__ __forceinline__ float fexp2(float x) {
#if __has_builtin(__builtin_amdgcn_exp2f)
    return __builtin_amdgcn_exp2f(x);
#else
    return exp2f(x);
#endif
}

__device__ __forceinline__ void gl16(const void* g, void* l) {
    __builtin_amdgcn_global_load_lds((const __attribute__((address_space(1))) unsigned int*)g,
                                     (__attribute__((address_space(3))) unsigned int*)l,
                                     16, 0, 0);
}

// MFMA conventions (HW-verified R1/R2/R5):
//  16x16x32: mfma(Af,Bf,C): C[i][j]=sum_c A[i][c]B[j][c]; A/B: lane(l15,lh) row=l15,
//            c=kc*32+lh*8+j; C/D: lane(l15,lh) reg jr = C[4*lh+jr][l15].
//  32x32x16: A/B: lane(l31,hi) row=l31, c=hi*8+j (K=16); C/D: col=lane&31,
//            row=(r&3)+8*(r>>2)+4*hi (r=0..15).
// Staged tiles: linear LDS dest (global_load_lds rule), inverse-swizzled GLOBAL
// source, same XOR on reads.

// ---------------------------------------------------------------------------
// K0a: x prep: xnbf = bf16(x/||x||); xT[b][d][s] = bf16(x) transposed; xnorm.
// ---------------------------------------------------------------------------
__global__ __launch_bounds__(256) void k0a_xprep(const float* __restrict__ x,
                                                 unsigned short* __restrict__ xnbf,
                                                 unsigned short* __restrict__ xT,
                                                 float* __restrict__ xnorm) {
    __shared__ __align__(16) unsigned int T2[128 * 32];
    const int b  = blockIdx.x >> 4;
    const int s0 = (blockIdx.x & 15) * 64;
    const int t  = threadIdx.x;
    const int rp = t >> 3;
    const int q  = t & 7;
    const int row0 = s0 + 2 * rp;
    const float* p0 = x + ((size_t)b * S_ + row0) * D_ + q * 16;
    const float* p1 = p0 + D_;
    f32x4 a[4], c[4];
    #pragma unroll
    for (int i = 0; i < 4; ++i) { a[i] = ((const f32x4*)p0)[i]; c[i] = ((const f32x4*)p1)[i]; }
    float sa = 0.f, sc = 0.f;
    #pragma unroll
    for (int i = 0; i < 4; ++i)
        #pragma unroll
        for (int j = 0; j < 4; ++j) { sa += a[i][j]*a[i][j]; sc += c[i][j]*c[i][j]; }
    sa += __shfl_xor(sa, 1); sa += __shfl_xor(sa, 2); sa += __shfl_xor(sa, 4);
    sc += __shfl_xor(sc, 1); sc += __shfl_xor(sc, 2); sc += __shfl_xor(sc, 4);
    const float na = sqrtf(sa), nc = sqrtf(sc);
    if (q == 0) {
        xnorm[(size_t)b*S_ + row0]     = na;
        xnorm[(size_t)b*S_ + row0 + 1] = nc;
    }
    const float ia = 1.0f / na, ic = 1.0f / nc;
    unsigned int pk[8];
    #pragma unroll
    for (int i = 0; i < 4; ++i) {
        pk[2*i]   = pk2(a[i][0]*ia, a[i][1]*ia);
        pk[2*i+1] = pk2(a[i][2]*ia, a[i][3]*ia);
    }
    *(u32x4*)(xnbf + ((size_t)b*S_ + row0)*D_ + q*16)     = *(u32x4*)&pk[0];
    *(u32x4*)(xnbf + ((size_t)b*S_ + row0)*D_ + q*16 + 8) = *(u32x4*)&pk[4];
    #pragma unroll
    for (int i = 0; i < 4; ++i) {
        pk[2*i]   = pk2(c[i][0]*ic, c[i][1]*ic);
        pk[2*i+1] = pk2(c[i][2]*ic, c[i][3]*ic);
    }
    *(u32x4*)(xnbf + ((size_t)b*S_ + row0 + 1)*D_ + q*16)     = *(u32x4*)&pk[0];
    *(u32x4*)(xnbf + ((size_t)b*S_ + row0 + 1)*D_ + q*16 + 8) = *(u32x4*)&pk[4];
    #pragma unroll
    for (int i = 0; i < 4; ++i)
        #pragma unroll
        for (int j = 0; j < 4; ++j) {
            const int d = q*16 + i*4 + j;
            *(unsigned int*)((char*)T2 + d*128 + ((rp*4) ^ (((d>>3)&7)<<4))) =
                pk2(a[i][j], c[i][j]);
        }
    __syncthreads();
    const int d  = t >> 1;
    const int hf = t & 1;
    unsigned short* dst = xT + ((size_t)(b*128 + d))*1024 + s0 + hf*32;
    #pragma unroll
    for (int cI = 0; cI < 4; ++cI) {
        const int sp0 = hf*16 + cI*4;
        u32x4 v = *(u32x4*)((char*)T2 + d*128 + ((sp0*4) ^ (((d>>3)&7)<<4)));
        *(u32x4*)(dst + cI*8) = v;
    }
}

// ---------------------------------------------------------------------------
// K0b: weight transposes to bf16.
// ---------------------------------------------------------------------------
__global__ __launch_bounds__(256) void k0b_wprep(const float* __restrict__ w1,
                                                 const float* __restrict__ w2,
                                                 const float* __restrict__ wp,
                                                 const float* __restrict__ wd1,
                                                 const float* __restrict__ wd2,
                                                 unsigned short* __restrict__ w1T,
                                                 unsigned short* __restrict__ w2T,
                                                 unsigned short* __restrict__ wpT,
                                                 unsigned short* __restrict__ wd1T,
                                                 unsigned short* __restrict__ wd2T) {
    __shared__ __align__(16) unsigned int T2[64 * 32];
    const int bi = blockIdx.x;
    const float* src; unsigned short* dst; int R, r0, c0;
    if (bi < 32) {
        src = w1; dst = w1T; R = 1024;
        r0 = (bi >> 1) * 64; c0 = (bi & 1) * 64;
    } else {
        const int k = (bi - 32) >> 2, qd = (bi - 32) & 3;
        const float* ss[4] = {w2, wp, wd1, wd2};
        unsigned short* dd[4] = {w2T, wpT, wd1T, wd2T};
        src = ss[k]; dst = dd[k]; R = 128;
        r0 = (qd >> 1) * 64; c0 = (qd & 1) * 64;
    }
    const int t = threadIdx.x;
    const int rp = t >> 3, q = t & 7;
    const float* p0 = src + (size_t)(r0 + 2*rp) * 128 + c0 + q*8;
    const float* p1 = p0 + 128;
    f32x4 a0 = ((const f32x4*)p0)[0], a1 = ((const f32x4*)p0)[1];
    f32x4 b0 = ((const f32x4*)p1)[0], b1 = ((const f32x4*)p1)[1];
    #pragma unroll
    for (int j = 0; j < 4; ++j) {
        int cc = q*8 + j;
        *(unsigned int*)((char*)T2 + cc*128 + ((rp*4) ^ (((cc>>3)&7)<<4))) = pk2(a0[j], b0[j]);
        cc = q*8 + 4 + j;
        *(unsigned int*)((char*)T2 + cc*128 + ((rp*4) ^ (((cc>>3)&7)<<4))) = pk2(a1[j], b1[j]);
    }
    __syncthreads();
    const int cI = t >> 2, qt = t & 3;
    unsigned short* od = dst + (size_t)(c0 + cI) * R + r0 + qt*16;
    #pragma unroll
    for (int u = 0; u < 2; ++u) {
        const int sp0 = qt*8 + u*4;
        u32x4 v = *(u32x4*)((char*)T2 + cI*128 + ((sp0*4) ^ (((cI>>3)&7)<<4)));
        *(u32x4*)(od + u*8) = v;
    }
}

// ---------------------------------------------------------------------------
// K12: fused proto pipeline (unchanged, known-good).
// ---------------------------------------------------------------------------
__global__ __launch_bounds__(512) void k12_proto(const unsigned short* __restrict__ xT,
                                                 const unsigned short* __restrict__ w1T,
                                                 const float* __restrict__ b_n1,
                                                 const unsigned short* __restrict__ w2T,
                                                 const float* __restrict__ b_n2,
                                                 float* __restrict__ out1,
                                                 unsigned short* __restrict__ pbf,
                                                 unsigned short* __restrict__ pbfT) {
    __shared__ __align__(16) unsigned short pool[2][2][128 * 64];
    __shared__ __align__(16) unsigned short GT[128][136];
    __shared__ float nrm[128][2];
    const int b = blockIdx.x;
    const int tid = threadIdx.x;
    const int w = tid >> 6, l = tid & 63, l15 = l & 15, lh = l >> 4;
    const int mb = (w & 3) * 32;
    const int db = (w >> 2) * 64;

    f32x4 acc[2][4] = {};

    #define STAGE_A(buf, itt)                                                        \
        { _Pragma("unroll")                                                          \
          for (int i = 0; i < 2; ++i) {                                              \
            const int s = tid + 512*i;                                               \
            const int r = s >> 3, chs = s & 7;                                       \
            gl16(w1T + (size_t)r*1024 + (itt)*64 + (chs ^ (r & 7))*8,                \
                 &pool[buf][0][s*8]);                                                \
            gl16(xT + ((size_t)(b*128 + r))*1024 + (itt)*64 + (chs ^ (r & 7))*8,     \
                 &pool[buf][1][s*8]);                                                \
          } }

    STAGE_A(0, 0)
    asm volatile("s_waitcnt vmcnt(0)");
    __syncthreads();
    int cur = 0;
    for (int it = 0; it < 16; ++it) {
        if (it < 15) {
            STAGE_A(cur ^ 1, it + 1)
        } else {
            #pragma unroll
            for (int i = 0; i < 4; ++i) {
                const int s = tid + 512*i;
                const int r = s >> 4, chs = s & 15;
                gl16(w2T + (size_t)r*128 + (chs ^ (r & 7))*8,
                     ((unsigned short*)pool[0]) + s*8);
            }
        }
        const unsigned short* WA = pool[cur][0];
        const unsigned short* XA = pool[cur][1];
        #pragma unroll
        for (int kc = 0; kc < 2; ++kc) {
            short8b Af[2], Bf[4];
            #pragma unroll
            for (int mt = 0; mt < 2; ++mt) {
                const int m = mb + mt*16 + l15;
                Af[mt] = *(const short8b*)(WA + m*64 + ((kc*4 + lh) ^ (m & 7))*8);
            }
            #pragma unroll
            for (int dt = 0; dt < 4; ++dt) {
                const int d = db + dt*16 + l15;
                Bf[dt] = *(const short8b*)(XA + d*64 + ((kc*4 + lh) ^ (d & 7))*8);
            }
            #pragma unroll
            for (int mt = 0; mt < 2; ++mt)
                #pragma unroll
                for (int dt = 0; dt < 4; ++dt)
                    acc[mt][dt] = __builtin_amdgcn_mfma_f32_16x16x32_bf16(Af[mt], Bf[dt], acc[mt][dt], 0, 0, 0);
        }
        asm volatile("s_waitcnt vmcnt(0)");
        __syncthreads();
        cur ^= 1;
    }
    #pragma unroll
    for (int mt = 0; mt < 2; ++mt)
        #pragma unroll
        for (int dt = 0; dt < 4; ++dt)
            #pragma unroll
            for (int u = 0; u < 2; ++u) {
                const int m = mb + mt*16 + lh*4 + 2*u;
                const int d = db + dt*16 + l15;
                const float v0 = gelu_exact(acc[mt][dt][2*u]   + b_n1[m]);
                const float v1 = gelu_exact(acc[mt][dt][2*u+1] + b_n1[m+1]);
                *(unsigned int*)((char*)&GT[0][0] + d*272 + m*2) = pk2(v0, v1);
            }
    __syncthreads();
    const unsigned short* W2 = (const unsigned short*)pool[0];
    f32x4 acc2[2][4] = {};
    #pragma unroll
    for (int kc = 0; kc < 4; ++kc) {
        short8b Af[2], Bf[4];
        #pragma unroll
        for (int nt = 0; nt < 2; ++nt) {
            const int n = mb + nt*16 + l15;
            Af[nt] = *(const short8b*)(W2 + n*128 + ((kc*4 + lh) ^ (n & 7))*8);
        }
        #pragma unroll
        for (int dt = 0; dt < 4; ++dt) {
            const int d = db + dt*16 + l15;
            Bf[dt] = *(const short8b*)((char*)&GT[0][0] + d*272 + kc*64 + lh*16);
        }
        #pragma unroll
        for (int nt = 0; nt < 2; ++nt)
            #pragma unroll
            for (int dt = 0; dt < 4; ++dt)
                acc2[nt][dt] = __builtin_amdgcn_mfma_f32_16x16x32_bf16(Af[nt], Bf[dt], acc2[nt][dt], 0, 0, 0);
    }
    #pragma unroll
    for (int nt = 0; nt < 2; ++nt) {
        #pragma unroll
        for (int jr = 0; jr < 4; ++jr) {
            const int n = mb + nt*16 + lh*4 + jr;
            const float bb = b_n2[n];
            float ps = 0.f;
            #pragma unroll
            for (int dt = 0; dt < 4; ++dt) {
                const int d = db + dt*16 + l15;
                const float v = acc2[nt][dt][jr] + bb;
                acc2[nt][dt][jr] = v;
                out1[((size_t)(b*128 + n))*128 + d] = v;
                ps += v * v;
            }
            ps += __shfl_xor(ps, 1); ps += __shfl_xor(ps, 2);
            ps += __shfl_xor(ps, 4); ps += __shfl_xor(ps, 8);
            if (l15 == 0) nrm[n][w >> 2] = ps;
        }
    }
    __syncthreads();
    unsigned short* TP = (unsigned short*)pool[1];
    #pragma unroll
    for (int nt = 0; nt < 2; ++nt)
        #pragma unroll
        for (int jr = 0; jr < 4; ++jr) {
            const int n = mb + nt*16 + lh*4 + jr;
            const float pin = 1.0f / sqrtf(nrm[n][0] + nrm[n][1]);
            #pragma unroll
            for (int dt = 0; dt < 4; ++dt) {
                const int d = db + dt*16 + l15;
                pbf[((size_t)(b*128 + n))*128 + d] = f2bf(acc2[nt][dt][jr] * pin);
            }
        }
    #pragma unroll
    for (int nt = 0; nt < 2; ++nt)
        #pragma unroll
        for (int dt = 0; dt < 4; ++dt)
            #pragma unroll
            for (int u = 0; u < 2; ++u) {
                const int n0 = mb + nt*16 + lh*4 + 2*u;
                const int d = db + dt*16 + l15;
                *(unsigned int*)((char*)TP + d*256 + ((n0*2) ^ ((d & 7) << 4))) =
                    pk2(acc2[nt][dt][2*u], acc2[nt][dt][2*u+1]);
            }
    __syncthreads();
    if (tid < 256) {
        const int d = tid >> 1, hf = tid & 1;
        #pragma unroll
        for (int cI = 0; cI < 8; ++cI) {
            short8b v = *(const short8b*)((char*)TP + d*256 + ((hf*128 + cI*16) ^ ((d & 7) << 4)));
            *(short8b*)(pbfT + (size_t)d*BN_ + b*128 + hf*64 + cI*8) = v;
        }
    }
}

// ---------------------------------------------------------------------------
// K4a: cosine attention. 256 blocks x 512 thr (8 waves).
// Block = 128 q x 1024-key half. Wave (qg = w&3: 32 q, kq = w>>2: 32-key half
// of every 64-key tile) -> ALL waves compute EVERY tile. 16 tiles.
// 32x32x16 MFMA; P stays in registers (cvt_pk + permlane32_swap).
// Epilogue: combine kq pair in LDS, store fp32 partials per key-half.
// ---------------------------------------------------------------------------
__global__ __launch_bounds__(512, 2) void k4a_attn(const unsigned short* __restrict__ xnbf,
                                                   const unsigned short* __restrict__ pbf,
                                                   const unsigned short* __restrict__ pbfT,
                                                   float* __restrict__ Op0,
                                                   float* __restrict__ Op1,
                                                   float* __restrict__ lpart) {
    __shared__ __align__(16) char smem[65536];          // Kb[2][64*128]us | Vb[2][128*64]us
    __shared__ float lbuf[128];
    unsigned short* Kb0 = (unsigned short*)smem;         // 16KB each buf
    unsigned short* Vb0 = (unsigned short*)(smem + 32768);
    const int tid = threadIdx.x;
    const int w = tid >> 6, l = tid & 63;
    const int l31 = l & 31, hi = l >> 5;
    const int qg = w & 3, kq = w >> 2;
    const int qblk = blockIdx.x >> 1, half = blockIdx.x & 1;
    const int qb = qblk * 128 + qg * 32;
    float* __restrict__ Opart = half ? Op1 : Op0;

    // X B-fragments resident: lane l31 = q row, c = hi*8+j per 16-d chunk kc
    short8b Xf[8];
    #pragma unroll
    for (int kc = 0; kc < 8; ++kc)
        Xf[kc] = *(const short8b*)(xnbf + (size_t)(qb + l31) * D_ + kc * 16 + hi * 8);

    // staging pointers: advance by constant per tile (i-unrolled, static idx)
    const unsigned short* pK[2];
    const unsigned short* pV[2];
    int sKa[2];
    #pragma unroll
    for (int i = 0; i < 2; ++i) {
        const int s = tid + 512 * i;
        sKa[i] = s;
        const int rK = s >> 4, cK = (s & 15) ^ (rK & 15);
        pK[i] = pbf + (size_t)(half * 1024 + rK) * D_ + cK * 8;
        const int dV = s >> 3, cV = (s & 7) ^ (dV & 7);
        pV[i] = pbfT + (size_t)dV * BN_ + half * 1024 + cV * 8;
    }

    #define STG(buf) {                                                        \
        unsigned short* KB_ = Kb0 + (buf) * (64 * 128);                       \
        unsigned short* VB_ = Vb0 + (buf) * (128 * 64);                       \
        _Pragma("unroll")                                                     \
        for (int i = 0; i < 2; ++i) {                                         \
            gl16(pK[i], KB_ + sKa[i] * 8);                                    \
            gl16(pV[i], VB_ + sKa[i] * 8);                                    \
            pK[i] += 64 * 128; pV[i] += 64;                                   \
        } }

    f32x16 acc[4] = {};
    float lsum = 0.f;

    STG(0)
    __syncthreads();
    for (int g = 0; g < 16; ++g) {
        if (g < 15) STG((g + 1) & 1)
        const unsigned short* KB = Kb0 + (g & 1) * (64 * 128);
        const unsigned short* VB = Vb0 + (g & 1) * (128 * 64);
        // QK^T (swapped): S = sim[key][q=l31], key_local = (r&3)+8*(r>>2)+4*hi
        f32x16 S = {};
        #pragma unroll
        for (int kc = 0; kc < 8; ++kc) {
            const int cs = ((kc * 2 + hi) ^ (l31 & 15)) * 8;
            short8b Kf = *(const short8b*)(KB + (kq * 32 + l31) * 128 + cs);
            S = __builtin_amdgcn_mfma_f32_32x32x16_bf16(Kf, Xf[kc], S, 0, 0, 0);
        }
        // p = exp(sim-1); pack bf16 (HW cvt_pk); permlane-redistribute -> A-frags
        float p[16];
        #pragma unroll
        for (int r = 0; r < 16; ++r) {
            p[r] = fexp2(S[r] * LOG2E - LOG2E);
            lsum += p[r];
        }
        short8b Pf[2];
        #pragma unroll
        for (int h = 0; h < 2; ++h) {
            unsigned int wA0 = cvtpk(p[8*h+0], p[8*h+1]);
            unsigned int wA1 = cvtpk(p[8*h+2], p[8*h+3]);
            unsigned int wB0 = cvtpk(p[8*h+4], p[8*h+5]);
            unsigned int wB1 = cvtpk(p[8*h+6], p[8*h+7]);
            asm("v_permlane32_swap_b32 %0, %1" : "+v"(wB0), "+v"(wA0));
            asm("v_permlane32_swap_b32 %0, %1" : "+v"(wB1), "+v"(wA1));
            u32x4 pw; pw[0] = wA0; pw[1] = wA1; pw[2] = wB0; pw[3] = wB1;
            Pf[h] = __builtin_bit_cast(short8b, pw);
        }
        // PV: acc[dt], C[q][d]; key chunk (8 keys) = kq*4 + kc2*2 + hi
        #pragma unroll
        for (int kc2 = 0; kc2 < 2; ++kc2) {
            #pragma unroll
            for (int dt = 0; dt < 4; ++dt) {
                const int d = dt * 32 + l31;
                short8b Vf = *(const short8b*)(VB + d * 64 + (((kq*4 + kc2*2 + hi) ^ (d & 7)) * 8));
                acc[dt] = __builtin_amdgcn_mfma_f32_32x32x16_bf16(Pf[kc2], Vf, acc[dt], 0, 0, 0);
            }
        }
        __syncthreads();
    }
    // lsum: lane l31 = q; fold hi halves
    lsum += __shfl_xor(lsum, 32);

    // combine kq pair through LDS (Obuf = whole smem: 128 q x 128 d fp32)
    float* Obuf = (float*)smem;
    if (kq == 0) {
        #pragma unroll
        for (int dt = 0; dt < 4; ++dt)
            #pragma unroll
            for (int r = 0; r < 16; ++r) {
                const int qr = (r & 3) + 8 * (r >> 2) + 4 * hi;
                Obuf[(qg * 32 + qr) * 128 + dt * 32 + l31] = acc[dt][r];
            }
        if (!hi) lbuf[qg * 32 + l31] = lsum;
    }
    __syncthreads();
    if (kq == 1) {
        #pragma unroll
        for (int dt = 0; dt < 4; ++dt)
            #pragma unroll
            for (int r = 0; r < 16; ++r) {
                const int qr = (r & 3) + 8 * (r >> 2) + 4 * hi;
                const float v = acc[dt][r] + Obuf[(qg * 32 + qr) * 128 + dt * 32 + l31];
                Opart[(size_t)(qb + qr) * D_ + dt * 32 + l31] = v;
            }
        if (!hi) lpart[half * BS_ + qb + l31] = lsum + lbuf[qg * 32 + l31];
    }
}

// ---------------------------------------------------------------------------
// K4b: pbm = bf16((O0+O1) / (l0+l1)).  512 blocks x 256 thr.
// ---------------------------------------------------------------------------
__global__ __launch_bounds__(256) void k4b_comb(const float* __restrict__ Op0,
                                                const float* __restrict__ Op1,
                                                const float* __restrict__ lpart,
                                                unsigned short* __restrict__ pbm) {
    const int t = blockIdx.x * 256 + threadIdx.x;
    const int row = t >> 3, d0 = (t & 7) * 16;
    const float inv = 1.0f / (lpart[row] + lpart[BS_ + row]);
    const float* a = Op0 + (size_t)row * D_ + d0;
    const float* b = Op1 + (size_t)row * D_ + d0;
    unsigned int wo[8];
    #pragma unroll
    for (int i = 0; i < 4; ++i) {
        f32x4 va = ((const f32x4*)a)[i];
        f32x4 vb = ((const f32x4*)b)[i];
        wo[2*i]   = pk2((va[0]+vb[0])*inv, (va[1]+vb[1])*inv);
        wo[2*i+1] = pk2((va[2]+vb[2])*inv, (va[3]+vb[3])*inv);
    }
    *(u32x4*)(pbm + (size_t)row * D_ + d0)     = *(u32x4*)&wo[0];
    *(u32x4*)(pbm + (size_t)row * D_ + d0 + 8) = *(u32x4*)&wo[4];
}

// ---------------------------------------------------------------------------
// K_res: out2 = x @ w_p + b_p (unchanged).
// ---------------------------------------------------------------------------
__global__ __launch_bounds__(256) void k_res_mfma(const unsigned short* __restrict__ xnbf,
                                                  const float* __restrict__ xnorm,
                                                  const unsigned short* __restrict__ wpT,
                                                  const float* __restrict__ bp,
                                                  float* __restrict__ out2) {
    __shared__ __align__(16) unsigned short XA[64 * 128];
    __shared__ __align__(16) unsigned short WB[128 * 128];
    const int tid = threadIdx.x;
    const int w = tid >> 6, l = tid & 63, l15 = l & 15, lh = l >> 4;
    const int r0 = blockIdx.x * 64;
    #pragma unroll
    for (int i = 0; i < 4; ++i) {
        const int s = tid + 256*i;
        const int r = s >> 4, chs = s & 15;
        gl16(xnbf + (size_t)(r0 + r)*128 + (chs ^ (r & 7))*8, XA + s*8);
    }
    #pragma unroll
    for (int i = 0; i < 8; ++i) {
        const int s = tid + 256*i;
        const int r = s >> 4, chs = s & 15;
        gl16(wpT + (size_t)r*128 + (chs ^ (r & 7))*8, WB + s*8);
    }
    asm volatile("s_waitcnt vmcnt(0)");
    __syncthreads();
    const int rb = w * 16;
    f32x4 acc[8] = {};
    #pragma unroll
    for (int kc = 0; kc < 4; ++kc) {
        const int r = rb + l15;
        short8b Af = *(const short8b*)(XA + r*128 + ((kc*4 + lh) ^ (r & 7))*8);
        #pragma unroll
        for (int cb = 0; cb < 8; ++cb) {
            const int c = cb*16 + l15;
            short8b Bf = *(const short8b*)(WB + c*128 + ((kc*4 + lh) ^ (c & 7))*8);
            acc[cb] = __builtin_amdgcn_mfma_f32_16x16x32_bf16(Af, Bf, acc[cb], 0, 0, 0);
        }
    }
    #pragma unroll
    for (int jr = 0; jr < 4; ++jr) {
        const int r = r0 + rb + lh*4 + jr;
        const float xn = xnorm[r];
        #pragma unroll
        for (int cb = 0; cb < 8; ++cb) {
            const int c = cb*16 + l15;
            out2[(size_t)r*128 + c] = xn * acc[cb][jr] + bp[c];
        }
    }
}

// ---------------------------------------------------------------------------
// K5: out0 = gelu(pbm @ w_d1 + b1) @ w_d2 + b2 + res.
// T1 overlays PA (phase-1 A-reads are wave-local rows) -> 80KB, 2 blocks/CU.
// ---------------------------------------------------------------------------
__global__ __launch_bounds__(256) void k5_mlp_mfma(const unsigned short* __restrict__ pbm,
                                                   const unsigned short* __restrict__ wd1T,
                                                   const float* __restrict__ b1,
                                                   const unsigned short* __restrict__ wd2T,
                                                   const float* __restrict__ b2,
                                                   const float* __restrict__ res,
                                                   float* __restrict__ out0) {
    __shared__ __align__(16) unsigned short PA[64 * 128];
    __shared__ __align__(16) unsigned short W1B[128 * 128];
    __shared__ __align__(16) unsigned short W2B[128 * 128];
    const int tid = threadIdx.x;
    const int w = tid >> 6, l = tid & 63, l15 = l & 15, lh = l >> 4;
    const int r0 = blockIdx.x * 64;
    #pragma unroll
    for (int i = 0; i < 4; ++i) {
        const int s = tid + 256*i;
        const int r = s >> 4, chs = s & 15;
        gl16(pbm + (size_t)(r0 + r)*128 + (chs ^ (r & 7))*8, PA + s*8);
    }
    #pragma unroll
    for (int i = 0; i < 8; ++i) {
        const int s = tid + 256*i;
        const int r = s >> 4, chs = s & 15;
        gl16(wd1T + (size_t)r*128 + (chs ^ (r & 7))*8, W1B + s*8);
        gl16(wd2T + (size_t)r*128 + (chs ^ (r & 7))*8, W2B + s*8);
    }
    asm volatile("s_waitcnt vmcnt(0)");
    __syncthreads();
    const int rb = w * 16;
    f32x4 acc1[8] = {};
    #pragma unroll
    for (int kc = 0; kc < 4; ++kc) {
        const int r = rb + l15;
        short8b Af = *(const short8b*)(PA + r*128 + ((kc*4 + lh) ^ (r & 7))*8);
        #pragma unroll
        for (int hb = 0; hb < 8; ++hb) {
            const int h = hb*16 + l15;
            short8b Bf = *(const short8b*)(W1B + h*128 + ((kc*4 + lh) ^ (h & 7))*8);
            acc1[hb] = __builtin_amdgcn_mfma_f32_16x16x32_bf16(Af, Bf, acc1[hb], 0, 0, 0);
        }
    }
    // gelu + bias -> T1 overlays PA (wave-local rows: safe after own reads)
    unsigned short* T1 = PA;
    __syncthreads();
    #pragma unroll
    for (int hb = 0; hb < 8; ++hb) {
        const int h = hb*16 + l15;
        const float bb = b1[h];
        #pragma unroll
        for (int jr = 0; jr < 4; ++jr) {
            const int r = rb + lh*4 + jr;
            const float v = gelu_exact(acc1[hb][jr] + bb);
            *(unsigned short*)((char*)T1 + r*256 + ((h*2) ^ ((r & 7) << 4))) = f2bf(v);
        }
    }
    __syncthreads();
    f32x4 acc2[8] = {};
    #pragma unroll
    for (int kc = 0; kc < 4; ++kc) {
        const int r = rb + l15;
        short8b Af = *(const short8b*)((char*)T1 + r*256 + ((kc*64 + lh*16) ^ ((r & 7) << 4)));
        #pragma unroll
        for (int cb = 0; cb < 8; ++cb) {
            const int c = cb*16 + l15;
            short8b Bf = *(const short8b*)(W2B + c*128 + ((kc*4 + lh) ^ (c & 7))*8);
            acc2[cb] = __builtin_amdgcn_mfma_f32_16x16x32_bf16(Af, Bf, acc2[cb], 0, 0, 0);
        }
    }
    #pragma unroll
    for (int cb = 0; cb < 8; ++cb) {
        const int c = cb*16 + l15;
        const float bb = b2[c];
        #pragma unroll
        for (int jr = 0; jr < 4; ++jr) {
            const int r = r0 + rb + lh*4 + jr;
            out0[(size_t)r*128 + c] = acc2[cb][jr] + bb + res[(size_t)r*128 + c];
        }
    }
}

// ---------------------------------------------------------------------------
extern "C" void kernel_launch(void* const* d_in, const int* in_sizes, int n_in,
                              void* d_out, int out_size, void* d_ws, size_t ws_size,
                              hipStream_t stream) {
    const float* x    = (const float*)d_in[0];
    const float* w_n1 = (const float*)d_in[2];
    const float* b_n1 = (const float*)d_in[3];
    const float* w_n2 = (const float*)d_in[4];
    const float* b_n2 = (const float*)d_in[5];
    const float* w_d1 = (const float*)d_in[6];
    const float* b_d1 = (const float*)d_in[7];
    const float* w_d2 = (const float*)d_in[8];
    const float* b_d2 = (const float*)d_in[9];
    const float* w_p  = (const float*)d_in[10];
    const float* b_p  = (const float*)d_in[11];

    float* out0 = (float*)d_out;                    // [16384,128] (scratch-reused as Opart0)
    float* out1 = out0 + (size_t)BS_ * D_;          // proto [2048,128]
    float* out2 = out1 + (size_t)BN_ * D_;          // res   [16384,128]

    char* ws = (char*)d_ws;
    unsigned short* xnbf = (unsigned short*)ws;                         // 4MB
    unsigned short* xT   = (unsigned short*)(ws + (4u << 20));          // 4MB
    unsigned short* pbm  = xT;                                          // overlay (xT dead after k12)
    float* xnorm         = (float*)(ws + (8u << 20));                   // 64KB
    unsigned short* w1T  = (unsigned short*)(ws + (8u << 20) + (64u << 10));
    unsigned short* w2T  = w1T + 128 * 1024;
    unsigned short* wpT  = w2T + 128 * 128;
    unsigned short* wd1T = wpT + 128 * 128;
    unsigned short* wd2T = wd1T + 128 * 128;
    unsigned short* pbf  = wd2T + 128 * 128;        // [2048][128] normalized
    unsigned short* pbfT = pbf + (size_t)BN_ * D_;  // [128][2048] unnormalized
    float* Opart0        = out0;                    // 8MB scratch (k5 overwrites last)
    float* Opart1        = (float*)(ws + (10u << 20));                  // 8MB
    float* lpart         = (float*)(ws + (18u << 20));                  // 2*64KB

    hipLaunchKernelGGL(k0a_xprep,   dim3(256), dim3(256), 0, stream, x, xnbf, xT, xnorm);
    hipLaunchKernelGGL(k0b_wprep,   dim3(48),  dim3(256), 0, stream, w_n1, w_n2, w_p, w_d1, w_d2,
                       w1T, w2T, wpT, wd1T, wd2T);
    hipLaunchKernelGGL(k12_proto,   dim3(16),  dim3(512), 0, stream, xT, w1T, b_n1, w2T, b_n2,
                       out1, pbf, pbfT);
    hipLaunchKernelGGL(k_res_mfma,  dim3(256), dim3(256), 0, stream, xnbf, xnorm, wpT, b_p, out2);
    hipLaunchKernelGGL(k4a_attn,    dim3(256), dim3(512), 0, stream, xnbf, pbf, pbfT,
                       Opart0, Opart1, lpart);
    hipLaunchKernelGGL(k4b_comb,    dim3(512), dim3(256), 0, stream, Opart0, Opart1, lpart, pbm);
    hipLaunchKernelGGL(k5_mlp_mfma, dim3(256), dim3(256), 0, stream, pbm, wd1T, b_d1, wd2T, b_d2,
                       out2, out0);
}